// Round 3
// baseline (1426.809 us; speedup 1.0000x reference)
//
#include <hip/hip_runtime.h>
#include <hip/hip_bf16.h>
#include <hip/hip_cooperative_groups.h>

namespace cg = cooperative_groups;

// GCN 2-layer + global_add_pool on MI355X.
// R9 = R8 with the host-side G bug fixed:
//  - out_size is an ELEMENT count (proven by E = in_sizes[1]/2 semantics),
//    so G = out_size/128 (=128). R8's /sizeof(float) gave G=32 and left 96
//    graph rows zero -> absmax 37.
//  - Everything else identical to R8: 17 dispatches -> 3 (pre_fused
//    cooperative CSR build, MFMA gemm, agg_fused cooperative
//    agg1+agg2/pool+gemm_small with atomic work stealing).

typedef _Float16 f16x8 __attribute__((ext_vector_type(8)));
typedef float f32x4 __attribute__((ext_vector_type(4)));

#define BCHUNK 4096

static __device__ __forceinline__ float f16lo(unsigned int u) {
    union { unsigned short s; _Float16 h; } c; c.s = (unsigned short)(u & 0xffff);
    return (float)c.h;
}
static __device__ __forceinline__ float f16hi(unsigned int u) {
    union { unsigned short s; _Float16 h; } c; c.s = (unsigned short)(u >> 16);
    return (float)c.h;
}
static __device__ __forceinline__ unsigned int pack2f16(float x, float y) {
    union { unsigned short s; _Float16 h; } a, b;
    a.h = (_Float16)x; b.h = (_Float16)y;
    return (unsigned int)a.s | ((unsigned int)b.s << 16);
}

// ---------------- fused preprocessing (cooperative) ----------------

struct PreP {
    const int* ei;
    int* counts; unsigned int* bedges; int* cnt; int* row_start; float* dinv;
    int* srcs; int* bsum; int* wc;
    const float* W1; _Float16* wfrag;
    float* P; _Float16* hb; _Float16* ob;
    int E, N, NB, NBLK, ncounts, nbc, nbn;
};

__global__ __launch_bounds__(256) void pre_fused(PreP p) {
    cg::grid_group grid = cg::this_grid();
    __shared__ int sh[256];
    int t = threadIdx.x;
    int gsz = gridDim.x;
    int gtid = blockIdx.x * 256 + t;
    int gstride = gsz * 256;

    // ---- phase 0 (no intra-kernel deps): zero P/sentinels/wc, wprep ----
    for (int i = gtid; i < 128 * 128; i += gstride) p.P[i] = 0.f;
    if (gtid < 64) {
        ((unsigned int*)(p.hb + (size_t)p.N * 128))[gtid] = 0u;
        ((unsigned int*)(p.ob + (size_t)p.N * 128))[gtid] = 0u;
    }
    if (gtid < 4) p.wc[gtid] = 0;
    for (int idx = gtid; idx < 2048; idx += gstride) {
        int lane = idx & 63, kc = (idx >> 6) & 3, nb = idx >> 8;
        int col = nb * 16 + (lane & 15);
        int krow = kc * 32 + (lane >> 4) * 8;
#pragma unroll
        for (int j = 0; j < 8; j++)
            p.wfrag[idx * 8 + j] = (_Float16)p.W1[(krow + j) * 128 + col];
    }

    // ---- bin_hist ----
    for (int blk = blockIdx.x; blk < p.NBLK; blk += gsz) {
        __syncthreads();
        for (int b = t; b < p.NB; b += 256) sh[b] = 0;
        __syncthreads();
        int base = blk * BCHUNK, end = min(p.E, base + BCHUNK);
        for (int e = base + t; e < end; e += 256)
            atomicAdd(&sh[p.ei[p.E + e] >> 8], 1);
        __syncthreads();
        for (int b = t; b < p.NB; b += 256) p.counts[b * p.NBLK + blk] = sh[b];
    }
    __threadfence(); grid.sync();

    // ---- block_sums(counts) ----
    for (int blk = blockIdx.x; blk < p.nbc; blk += gsz) {
        __syncthreads();
        int base = blk * 1024; int v = 0;
#pragma unroll
        for (int i = 0; i < 4; i++) {
            int idx = base + t * 4 + i;
            if (idx < p.ncounts) v += p.counts[idx];
        }
        sh[t] = v; __syncthreads();
        for (int off = 128; off > 0; off >>= 1) {
            if (t < off) sh[t] += sh[t + off];
            __syncthreads();
        }
        if (t == 0) p.bsum[blk] = sh[0];
    }
    __threadfence(); grid.sync();

    // ---- scan_bsum(nbc) ----
    if (blockIdx.x == 0 && t < 64) {
        int lane = t;
        int v = (lane < p.nbc) ? p.bsum[lane] : 0;
        int incl = v;
#pragma unroll
        for (int off = 1; off < 64; off *= 2) {
            int u = __shfl_up(incl, off);
            if (lane >= off) incl += u;
        }
        if (lane < p.nbc) p.bsum[lane] = incl - v;
    }
    __threadfence(); grid.sync();

    // ---- scan_apply(counts) ----
    for (int blk = blockIdx.x; blk < p.nbc; blk += gsz) {
        __syncthreads();
        int base = blk * 1024; int loc[4]; int v = 0;
#pragma unroll
        for (int i = 0; i < 4; i++) {
            int idx = base + t * 4 + i;
            loc[i] = (idx < p.ncounts) ? p.counts[idx] : 0;
            v += loc[i];
        }
        sh[t] = v; __syncthreads();
        for (int off = 1; off < 256; off *= 2) {
            int u = (t >= off) ? sh[t - off] : 0;
            __syncthreads();
            sh[t] += u;
            __syncthreads();
        }
        int excl = sh[t] - v + p.bsum[blk];
#pragma unroll
        for (int i = 0; i < 4; i++) {
            int idx = base + t * 4 + i;
            if (idx < p.ncounts) { p.counts[idx] = excl; excl += loc[i]; }
        }
    }
    __threadfence(); grid.sync();

    // ---- bin_scatter ----
    for (int blk = blockIdx.x; blk < p.NBLK; blk += gsz) {
        __syncthreads();
        for (int b = t; b < p.NB; b += 256) sh[b] = p.counts[b * p.NBLK + blk];
        __syncthreads();
        int base = blk * BCHUNK, end = min(p.E, base + BCHUNK);
        for (int e = base + t; e < end; e += 256) {
            int s = p.ei[e];
            int d = p.ei[p.E + e];
            int pos = atomicAdd(&sh[d >> 8], 1);
            p.bedges[pos] = (unsigned int)s | ((unsigned int)(d & 255) << 16);
        }
    }
    __threadfence(); grid.sync();

    // ---- deg_buckets ----
    for (int b = blockIdx.x; b < p.NB; b += gsz) {
        __syncthreads();
        sh[t] = 0; __syncthreads();
        int bstart = p.counts[b * p.NBLK];
        int bend = (b + 1 < p.NB) ? p.counts[(b + 1) * p.NBLK] : p.E;
        for (int i = bstart + t; i < bend; i += 256)
            atomicAdd(&sh[p.bedges[i] >> 16], 1);
        __syncthreads();
        int node = (b << 8) + t;
        if (node < p.N) p.cnt[node] = sh[t];
    }
    __threadfence(); grid.sync();

    // ---- block_sums_pad(cnt) ----
    for (int blk = blockIdx.x; blk < p.nbn; blk += gsz) {
        __syncthreads();
        int base = blk * 1024; int v = 0;
#pragma unroll
        for (int i = 0; i < 4; i++) {
            int idx = base + t * 4 + i;
            if (idx < p.N) v += (p.cnt[idx] + 7) & ~7;
        }
        sh[t] = v; __syncthreads();
        for (int off = 128; off > 0; off >>= 1) {
            if (t < off) sh[t] += sh[t + off];
            __syncthreads();
        }
        if (t == 0) p.bsum[blk] = sh[0];
    }
    __threadfence(); grid.sync();

    // ---- scan_bsum(nbn) ----
    if (blockIdx.x == 0 && t < 64) {
        int lane = t;
        int v = (lane < p.nbn) ? p.bsum[lane] : 0;
        int incl = v;
#pragma unroll
        for (int off = 1; off < 64; off *= 2) {
            int u = __shfl_up(incl, off);
            if (lane >= off) incl += u;
        }
        if (lane < p.nbn) p.bsum[lane] = incl - v;
    }
    __threadfence(); grid.sync();

    // ---- scan_nodes ----
    for (int blk = blockIdx.x; blk < p.nbn; blk += gsz) {
        __syncthreads();
        int base = blk * 1024; int loc[4], pc[4]; int v = 0;
#pragma unroll
        for (int i = 0; i < 4; i++) {
            int idx = base + t * 4 + i;
            loc[i] = (idx < p.N) ? p.cnt[idx] : 0;
            pc[i] = (loc[i] + 7) & ~7;
            v += pc[i];
        }
        sh[t] = v; __syncthreads();
        for (int off = 1; off < 256; off *= 2) {
            int u = (t >= off) ? sh[t - off] : 0;
            __syncthreads();
            sh[t] += u;
            __syncthreads();
        }
        int excl = sh[t] - v + p.bsum[blk];
#pragma unroll
        for (int i = 0; i < 4; i++) {
            int idx = base + t * 4 + i;
            if (idx < p.N) {
                p.row_start[idx] = excl;
                p.dinv[idx] = rsqrtf((float)loc[i] + 1.0f);
                excl += pc[i];
            }
        }
    }
    __threadfence(); grid.sync();

    // ---- fill_buckets (+ sentinel pad) ----
    for (int b = blockIdx.x; b < p.NB; b += gsz) {
        __syncthreads();
        int node = (b << 8) + t;
        sh[t] = (node < p.N) ? p.row_start[node] : 0;
        __syncthreads();
        int bstart = p.counts[b * p.NBLK];
        int bend = (b + 1 < p.NB) ? p.counts[(b + 1) * p.NBLK] : p.E;
        for (int i = bstart + t; i < bend; i += 256) {
            unsigned int pkt = p.bedges[i];
            int pos = atomicAdd(&sh[pkt >> 16], 1);
            p.srcs[pos] = (int)(pkt & 0xffffu);
        }
        if (node < p.N) {
            int c = p.cnt[node];
            int e0 = p.row_start[node] + c;
            int e1 = p.row_start[node] + ((c + 7) & ~7);
            for (int j = e0; j < e1; j++) p.srcs[j] = p.N;  // sentinel zero row
        }
    }
}

// ---------------- GEMM: C = dinv[row] * (A @ W), fp16 MFMA ----------------
__global__ __launch_bounds__(256) void gemm_mfma_f32in(const float* __restrict__ A,
                                                       const _Float16* __restrict__ wfrag,
                                                       const float* __restrict__ dinv,
                                                       _Float16* __restrict__ C, int M) {
    __shared__ _Float16 As[128 * 136];
    int t = threadIdx.x;
    int row0 = blockIdx.x * 128;

    const float4* A4 = (const float4*)A;
#pragma unroll
    for (int it = 0; it < 16; it++) {
        int v = it * 256 + t;
        int row = v >> 5;
        int seg = v & 31;
        float4 val = make_float4(0.f, 0.f, 0.f, 0.f);
        if (row0 + row < M) val = A4[(size_t)(row0 + row) * 32 + seg];
        _Float16* pp = &As[row * 136 + seg * 4];
        pp[0] = (_Float16)val.x; pp[1] = (_Float16)val.y;
        pp[2] = (_Float16)val.z; pp[3] = (_Float16)val.w;
    }
    __syncthreads();

    int wv = t >> 6;
    int lane = t & 63;
    int lrow = lane & 15;
    int lq = lane >> 4;

    f32x4 acc[2][8];
#pragma unroll
    for (int i = 0; i < 2; i++)
#pragma unroll
        for (int j = 0; j < 8; j++) acc[i][j] = (f32x4){0.f, 0.f, 0.f, 0.f};

#pragma unroll
    for (int kc = 0; kc < 4; kc++) {
        int k0 = kc * 32;
        f16x8 a0 = *((const f16x8*)&As[(wv * 32 + lrow) * 136 + k0 + lq * 8]);
        f16x8 a1 = *((const f16x8*)&As[(wv * 32 + 16 + lrow) * 136 + k0 + lq * 8]);
#pragma unroll
        for (int nb = 0; nb < 8; nb++) {
            f16x8 b = ((const f16x8*)wfrag)[(nb * 4 + kc) * 64 + lane];
            acc[0][nb] = __builtin_amdgcn_mfma_f32_16x16x32_f16(a0, b, acc[0][nb], 0, 0, 0);
            acc[1][nb] = __builtin_amdgcn_mfma_f32_16x16x32_f16(a1, b, acc[1][nb], 0, 0, 0);
        }
    }

#pragma unroll
    for (int ti = 0; ti < 2; ti++) {
#pragma unroll
        for (int r = 0; r < 4; r++) {
            int row = row0 + wv * 32 + ti * 16 + lq * 4 + r;
            if (row < M) {
                float dv = dinv[row];
#pragma unroll
                for (int nb = 0; nb < 8; nb++)
                    C[(size_t)row * 128 + nb * 16 + lrow] = (_Float16)(acc[ti][nb][r] * dv);
            }
        }
    }
}

// ---------------- fused agg1 + agg2/pool + gemm_small (cooperative) ----------------

struct AggP {
    const _Float16* hb; _Float16* ob;
    const int* srcs; const int* row_start; const int* cnt; const float* dinv;
    const float* b1; const int* batch;
    float* P; const float* W2; const float* b2; float* out;
    int* wc; int n; int G;
};

static __device__ __forceinline__ void gather8(const unsigned int* __restrict__ h2,
                                               const int* __restrict__ sbase,
                                               int nit, int lane,
                                               float& rx, float& ry) {
    float ax = 0.f, ay = 0.f, bx = 0.f, by = 0.f;
    const int4* sp = (const int4*)sbase;
    int4 sa = {}, sb = {};
    if (nit > 0) { sa = sp[0]; sb = sp[1]; }
    for (int it = 0; it < nit; it++) {
        int4 ca = sa, cb = sb;
        int nx = (it + 1 < nit) ? it + 1 : it;   // branchless src prefetch
        sa = sp[nx * 2]; sb = sp[nx * 2 + 1];
        unsigned int v0 = h2[(size_t)(unsigned)ca.x * 64 + lane];
        unsigned int v1 = h2[(size_t)(unsigned)ca.y * 64 + lane];
        unsigned int v2 = h2[(size_t)(unsigned)ca.z * 64 + lane];
        unsigned int v3 = h2[(size_t)(unsigned)ca.w * 64 + lane];
        unsigned int v4 = h2[(size_t)(unsigned)cb.x * 64 + lane];
        unsigned int v5 = h2[(size_t)(unsigned)cb.y * 64 + lane];
        unsigned int v6 = h2[(size_t)(unsigned)cb.z * 64 + lane];
        unsigned int v7 = h2[(size_t)(unsigned)cb.w * 64 + lane];
        ax += f16lo(v0); ay += f16hi(v0);
        bx += f16lo(v1); by += f16hi(v1);
        ax += f16lo(v2); ay += f16hi(v2);
        bx += f16lo(v3); by += f16hi(v3);
        ax += f16lo(v4); ay += f16hi(v4);
        bx += f16lo(v5); by += f16hi(v5);
        ax += f16lo(v6); ay += f16hi(v6);
        bx += f16lo(v7); by += f16hi(v7);
    }
    rx = ax + bx; ry = ay + by;
}

__global__ __launch_bounds__(256) void agg_fused(AggP p) {
    cg::grid_group grid = cg::this_grid();
    __shared__ float red[4][128];
    __shared__ float prow2[2][128];
    __shared__ int svb;
    int t = threadIdx.x, wv = t >> 6, lane = t & 63;
    int nvb = (p.n + 3) >> 2;

    // ---- agg1: ob = dinv * relu(dn*(sum+self) + b1) ----
    const unsigned int* hh = (const unsigned int*)p.hb;
    while (true) {
        __syncthreads();
        if (t == 0) svb = atomicAdd(&p.wc[0], 1);
        __syncthreads();
        int vb = svb;
        if (vb >= nvb) break;
        int node = vb * 4 + wv;
        if (node < p.n) {
            int s0 = p.row_start[node], c = p.cnt[node], nit = (c + 7) >> 3;
            float dn = p.dinv[node];
            unsigned int hs = hh[(size_t)node * 64 + lane];
            float ax, ay;
            gather8(hh, p.srcs + s0, nit, lane, ax, ay);
            ax += f16lo(hs); ay += f16hi(hs);
            float2 bv = ((const float2*)p.b1)[lane];
            float ox = fmaxf(fmaf(dn, ax, bv.x), 0.f) * dn;
            float oy = fmaxf(fmaf(dn, ay, bv.y), 0.f) * dn;
            ((unsigned int*)p.ob)[(size_t)node * 64 + lane] = pack2f16(ox, oy);
        }
    }
    __threadfence(); grid.sync();

    // ---- agg2 + pool ----
    const unsigned int* oo = (const unsigned int*)p.ob;
    while (true) {
        __syncthreads();
        if (t == 0) svb = atomicAdd(&p.wc[1], 1);
        __syncthreads();
        int vb = svb;
        if (vb >= nvb) break;
        int base = vb * 4, node = base + wv;
        float tx = 0.f, ty = 0.f;
        int g = -1;
        if (node < p.n) {
            g = p.batch[node];
            int s0 = p.row_start[node], c = p.cnt[node], nit = (c + 7) >> 3;
            float dn = p.dinv[node];
            unsigned int hs = oo[(size_t)node * 64 + lane];
            float ax, ay;
            gather8(oo, p.srcs + s0, nit, lane, ax, ay);
            ax += f16lo(hs); ay += f16hi(hs);
            tx = dn * ax; ty = dn * ay;
        }
        int lastn = min(base + 3, p.n - 1);
        bool uniform = (base < p.n) && (p.batch[base] == p.batch[lastn]) && (base + 3 < p.n);
        if (uniform) {
            red[wv][lane * 2 + 0] = tx;
            red[wv][lane * 2 + 1] = ty;
            __syncthreads();
            if (wv == 0) {
                float sx = red[0][lane * 2] + red[1][lane * 2] + red[2][lane * 2] + red[3][lane * 2];
                float sy = red[0][lane * 2 + 1] + red[1][lane * 2 + 1] + red[2][lane * 2 + 1] + red[3][lane * 2 + 1];
                atomicAdd(&p.P[g * 128 + lane * 2 + 0], sx);
                atomicAdd(&p.P[g * 128 + lane * 2 + 1], sy);
            }
            // loop-top __syncthreads protects red reuse
        } else if (node < p.n) {
            atomicAdd(&p.P[g * 128 + lane * 2 + 0], tx);
            atomicAdd(&p.P[g * 128 + lane * 2 + 1], ty);
        }
    }
    __threadfence(); grid.sync();

    // ---- out = P @ W2 + n_g*b2 (2 graphs per block) ----
    int nvb2 = (p.G + 1) >> 1;
    for (int vb = blockIdx.x; vb < nvb2; vb += gridDim.x) {
        __syncthreads();
        int half = t >> 7, c = t & 127;
        int g = vb * 2 + half;
        if (g < p.G) prow2[half][c] = p.P[g * 128 + c];
        __syncthreads();
        if (g < p.G) {
            int lo = 0, hi = p.n;
            while (lo < hi) { int mid = (lo + hi) >> 1; if (p.batch[mid] < g) lo = mid + 1; else hi = mid; }
            int start = lo;
            hi = p.n;
            while (lo < hi) { int mid = (lo + hi) >> 1; if (p.batch[mid] < g + 1) lo = mid + 1; else hi = mid; }
            float ng = (float)(lo - start);
            float acc = 0.f;
#pragma unroll 8
            for (int k = 0; k < 128; k++) acc = fmaf(prow2[half][k], p.W2[k * 128 + c], acc);
            p.out[g * 128 + c] = acc + ng * p.b2[c];
        }
    }
}

extern "C" void kernel_launch(void* const* d_in, const int* in_sizes, int n_in,
                              void* d_out, int out_size, void* d_ws, size_t ws_size,
                              hipStream_t stream) {
    const float* x  = (const float*)d_in[0];
    const int*   ei = (const int*)d_in[1];
    const int*   batch = (const int*)d_in[2];
    const float* W1 = (const float*)d_in[3];
    const float* b1 = (const float*)d_in[4];
    const float* W2 = (const float*)d_in[5];
    const float* b2 = (const float*)d_in[6];
    float* out = (float*)d_out;

    const int N = in_sizes[2];       // 50000 (assumed <= 65536)
    const int E = in_sizes[1] / 2;   // 800000
    const int G = out_size / 128;    // out_size is ELEMENT count -> 128 graphs

    const int NB = (N + 255) >> 8;              // 196 buckets
    const int NBLK = (E + BCHUNK - 1) / BCHUNK; // 196 chunks
    const int ncounts = NB * NBLK;
    const int SRP = E + 7 * N + 16;             // padded srcs capacity

    // workspace layout (hb/ob have N+8 rows; row N is the sentinel zero row)
    _Float16* hb = (_Float16*)d_ws;                  // (N+8)*128 halves
    _Float16* ob = hb + (size_t)(N + 8) * 128;       // (N+8)*128 halves
    int* cnt  = (int*)(ob + (size_t)(N + 8) * 128);  // N
    int* row_start = cnt + N;                        // N
    float* dinv    = (float*)(row_start + N);        // N
    int* srcs      = (int*)(dinv + N);               // SRP
    unsigned int* bedges = (unsigned int*)(srcs + SRP); // E
    int* counts    = (int*)(bedges + E);             // NB*NBLK
    _Float16* wfrag1 = (_Float16*)(counts + ncounts);// 128*128
    float* P       = (float*)(wfrag1 + 128 * 128);   // 128*128 f32
    int* bsum      = (int*)(P + 128 * 128);          // <=64
    int* wc        = bsum + 64;                      // 4 work counters

    const int nbc = (ncounts + 1023) / 1024;  // <=64
    const int nbn = (N + 1023) / 1024;        // <=64

    // co-resident grid sizing (one-time occupancy query, 256 CUs on MI355X)
    static int blkA = 0, blkC = 0;
    if (blkA == 0) {
        int a = 0, c = 0;
        hipOccupancyMaxActiveBlocksPerMultiprocessor(&a, pre_fused, 256, 0);
        hipOccupancyMaxActiveBlocksPerMultiprocessor(&c, agg_fused, 256, 0);
        if (a < 1) a = 1;
        if (c < 1) c = 1;
        blkA = a * 256;
        blkC = c * 256;
        if (blkC > 2048) blkC = 2048;
    }
    int GA = (NBLK > NB) ? NBLK : NB;
    if (GA > blkA) GA = blkA;
    int GC = blkC;

    PreP pp = {ei, counts, bedges, cnt, row_start, dinv, srcs, bsum, wc,
               W1, wfrag1, P, hb, ob, E, N, NB, NBLK, ncounts, nbc, nbn};
    void* pargs[] = {&pp};
    hipLaunchCooperativeKernel(pre_fused, dim3(GA), dim3(256), pargs, 0, stream);

    gemm_mfma_f32in<<<(N + 127) / 128, 256, 0, stream>>>(x, wfrag1, dinv, hb, N);

    AggP ap = {hb, ob, srcs, row_start, cnt, dinv, b1, batch,
               P, W2, b2, out, wc, N, G};
    void* aargs[] = {&ap};
    hipLaunchCooperativeKernel(agg_fused, dim3(GC), dim3(256), aargs, 0, stream);
}

// Round 4
// 244.366 us; speedup vs baseline: 5.8388x; 5.8388x over previous
//
#include <hip/hip_runtime.h>
#include <hip/hip_bf16.h>

// GCN 2-layer + global_add_pool on MI355X.
// R10: back out R9's cooperative/work-stealing regression (single-address
// atomic counter across 8 XCDs = ~1 ms of cacheline ping-pong; grid.sync
// costlier than the launches it replaced). Keep R7's proven agg/gemm
// kernels verbatim; compress preprocessing 13 stages -> 6 ordinary kernels:
//  - prep0: bucket hist + node degree (distributed atomics on cnt[dst],
//    50k addresses) + P/sentinel zeroing + wprep in one pass (deletes
//    deg_buckets and its serial dependency on the scatter).
//  - sums2/scan2/apply2: counts-scan and node-scan run as block-range-split
//    halves of 3 kernels (6 launches -> 3).
//  - bin_scatter / fill_buckets unchanged.
// 17 launches -> 11, dependency chain 10 -> 6.

typedef _Float16 f16x8 __attribute__((ext_vector_type(8)));
typedef float f32x4 __attribute__((ext_vector_type(4)));

#define BCHUNK 4096

static __device__ __forceinline__ float f16lo(unsigned int u) {
    union { unsigned short s; _Float16 h; } c; c.s = (unsigned short)(u & 0xffff);
    return (float)c.h;
}
static __device__ __forceinline__ float f16hi(unsigned int u) {
    union { unsigned short s; _Float16 h; } c; c.s = (unsigned short)(u >> 16);
    return (float)c.h;
}
static __device__ __forceinline__ unsigned int pack2f16(float x, float y) {
    union { unsigned short s; _Float16 h; } a, b;
    a.h = (_Float16)x; b.h = (_Float16)y;
    return (unsigned int)a.s | ((unsigned int)b.s << 16);
}

// ---------------- prep0: hist + degree + zeroing + wprep ----------------
__global__ __launch_bounds__(256) void prep0(const int* __restrict__ ei,
                                             const float* __restrict__ W1,
                                             _Float16* __restrict__ wfrag,
                                             float* __restrict__ P,
                                             _Float16* __restrict__ hb,
                                             _Float16* __restrict__ ob,
                                             int* __restrict__ cnt,
                                             int* __restrict__ counts,
                                             int E, int N, int NB, int NBLK) {
    __shared__ int hist[256];
    int t = threadIdx.x, blk = blockIdx.x;
    int gtid = blk * 256 + t;
    int gstride = gridDim.x * 256;

    // zero P (16384 f32), sentinel rows, wprep (2048 threads)
    for (int i = gtid; i < 128 * 128; i += gstride) P[i] = 0.f;
    if (gtid < 64) {
        ((unsigned int*)(hb + (size_t)N * 128))[gtid] = 0u;
        ((unsigned int*)(ob + (size_t)N * 128))[gtid] = 0u;
    }
    if (gtid < 2048) {
        int lane = gtid & 63, kc = (gtid >> 6) & 3, nb = gtid >> 8;
        int col = nb * 16 + (lane & 15);
        int krow = kc * 32 + (lane >> 4) * 8;
#pragma unroll
        for (int j = 0; j < 8; j++)
            wfrag[gtid * 8 + j] = (_Float16)W1[(krow + j) * 128 + col];
    }

    // bucket hist (LDS) + node degree (distributed global atomics)
    for (int b = t; b < NB; b += 256) hist[b] = 0;
    __syncthreads();
    int base = blk * BCHUNK;
    int end = min(E, base + BCHUNK);
    for (int e = base + t; e < end; e += 256) {
        int d = ei[E + e];
        atomicAdd(&hist[d >> 8], 1);
        atomicAdd(&cnt[d], 1);
    }
    __syncthreads();
    for (int b = t; b < NB; b += 256) counts[b * NBLK + blk] = hist[b];
}

// ---------------- sums2: block sums for counts (A) and padded cnt (B) ----------------
__global__ __launch_bounds__(256) void sums2(const int* __restrict__ counts,
                                             const int* __restrict__ cnt,
                                             int* __restrict__ bsum,
                                             int ncounts, int N, int nbc) {
    __shared__ int s[256];
    int t = threadIdx.x;
    bool isA = (int)blockIdx.x < nbc;
    int blk = isA ? blockIdx.x : blockIdx.x - nbc;
    int base = blk * 1024;
    int v = 0;
#pragma unroll
    for (int i = 0; i < 4; i++) {
        int idx = base + t * 4 + i;
        if (isA) { if (idx < ncounts) v += counts[idx]; }
        else     { if (idx < N) v += (cnt[idx] + 7) & ~7; }
    }
    s[t] = v;
    __syncthreads();
    for (int off = 128; off > 0; off >>= 1) {
        if (t < off) s[t] += s[t + off];
        __syncthreads();
    }
    if (t == 0) bsum[(isA ? 0 : 64) + blk] = s[0];
}

// ---------------- scan2: wave 0 scans bsum[0:nbc), wave 1 scans bsum[64:64+nbn) ----------------
__global__ void scan2(int* __restrict__ bsum, int nbc, int nbn) {
    int w = threadIdx.x >> 6, lane = threadIdx.x & 63;
    int off0 = w ? 64 : 0;
    int n = w ? nbn : nbc;
    int v = (lane < n) ? bsum[off0 + lane] : 0;
    int incl = v;
#pragma unroll
    for (int off = 1; off < 64; off *= 2) {
        int u = __shfl_up(incl, off);
        if (lane >= off) incl += u;
    }
    if (lane < n) bsum[off0 + lane] = incl - v;  // exclusive
}

// ---------------- apply2: scan_apply(counts) [A] + scan_nodes [B] ----------------
__global__ __launch_bounds__(256) void apply2(int* __restrict__ counts,
                                              const int* __restrict__ cnt,
                                              int* __restrict__ row_start,
                                              float* __restrict__ dinv,
                                              const int* __restrict__ bsum,
                                              int ncounts, int N, int nbc) {
    __shared__ int s[256];
    int t = threadIdx.x;
    bool isA = (int)blockIdx.x < nbc;
    int blk = isA ? blockIdx.x : blockIdx.x - nbc;
    int base = blk * 1024;
    int loc[4], pc[4];
    int v = 0;
#pragma unroll
    for (int i = 0; i < 4; i++) {
        int idx = base + t * 4 + i;
        if (isA) {
            loc[i] = (idx < ncounts) ? counts[idx] : 0;
            pc[i] = loc[i];
        } else {
            loc[i] = (idx < N) ? cnt[idx] : 0;
            pc[i] = (loc[i] + 7) & ~7;
        }
        v += pc[i];
    }
    s[t] = v;
    __syncthreads();
    for (int off = 1; off < 256; off *= 2) {
        int u = (t >= off) ? s[t - off] : 0;
        __syncthreads();
        s[t] += u;
        __syncthreads();
    }
    int excl = s[t] - v + bsum[(isA ? 0 : 64) + blk];
#pragma unroll
    for (int i = 0; i < 4; i++) {
        int idx = base + t * 4 + i;
        if (isA) {
            if (idx < ncounts) { counts[idx] = excl; excl += pc[i]; }
        } else {
            if (idx < N) {
                row_start[idx] = excl;
                dinv[idx] = rsqrtf((float)loc[i] + 1.0f);
                excl += pc[i];
            }
        }
    }
}

// ---------------- bin_scatter ----------------
__global__ __launch_bounds__(256) void bin_scatter(const int* __restrict__ ei,
                                                   const int* __restrict__ counts,
                                                   unsigned int* __restrict__ bedges,
                                                   int E, int NB, int NBLK) {
    __shared__ int lcur[256];
    int t = threadIdx.x, blk = blockIdx.x;
    for (int b = t; b < NB; b += 256) lcur[b] = counts[b * NBLK + blk];
    __syncthreads();
    int base = blk * BCHUNK;
    int end = min(E, base + BCHUNK);
    for (int e = base + t; e < end; e += 256) {
        int s = ei[e];
        int d = ei[E + e];
        int pos = atomicAdd(&lcur[d >> 8], 1);
        bedges[pos] = (unsigned int)s | ((unsigned int)(d & 255) << 16);
    }
}

// ---------------- fill_buckets (+ sentinel pad) ----------------
__global__ __launch_bounds__(256) void fill_buckets(const unsigned int* __restrict__ bedges,
                                                    const int* __restrict__ counts,
                                                    const int* __restrict__ row_start,
                                                    const int* __restrict__ cnt,
                                                    int* __restrict__ srcs,
                                                    int E, int N, int NB, int NBLK) {
    __shared__ int lcur[256];
    int b = blockIdx.x, t = threadIdx.x;
    int node = (b << 8) + t;
    lcur[t] = (node < N) ? row_start[node] : 0;
    __syncthreads();
    int bstart = counts[b * NBLK];
    int bend = (b + 1 < NB) ? counts[(b + 1) * NBLK] : E;
    for (int i = bstart + t; i < bend; i += 256) {
        unsigned int p = bedges[i];
        int pos = atomicAdd(&lcur[p >> 16], 1);
        srcs[pos] = (int)(p & 0xffffu);
    }
    if (node < N) {
        int c = cnt[node];
        int e0 = row_start[node] + c;
        int e1 = row_start[node] + ((c + 7) & ~7);
        for (int j = e0; j < e1; j++) srcs[j] = N;  // sentinel: zero row
    }
}

// ---------------- GEMM: C = dinv[row] * (A @ W), fp16 MFMA ----------------
__global__ __launch_bounds__(256) void gemm_mfma_f32in(const float* __restrict__ A,
                                                       const _Float16* __restrict__ wfrag,
                                                       const float* __restrict__ dinv,
                                                       _Float16* __restrict__ C, int M) {
    __shared__ _Float16 As[128 * 136];
    int t = threadIdx.x;
    int row0 = blockIdx.x * 128;

    const float4* A4 = (const float4*)A;
#pragma unroll
    for (int it = 0; it < 16; it++) {
        int v = it * 256 + t;
        int row = v >> 5;
        int seg = v & 31;
        float4 val = make_float4(0.f, 0.f, 0.f, 0.f);
        if (row0 + row < M) val = A4[(size_t)(row0 + row) * 32 + seg];
        _Float16* pp = &As[row * 136 + seg * 4];
        pp[0] = (_Float16)val.x; pp[1] = (_Float16)val.y;
        pp[2] = (_Float16)val.z; pp[3] = (_Float16)val.w;
    }
    __syncthreads();

    int wv = t >> 6;
    int lane = t & 63;
    int lrow = lane & 15;
    int lq = lane >> 4;

    f32x4 acc[2][8];
#pragma unroll
    for (int i = 0; i < 2; i++)
#pragma unroll
        for (int j = 0; j < 8; j++) acc[i][j] = (f32x4){0.f, 0.f, 0.f, 0.f};

#pragma unroll
    for (int kc = 0; kc < 4; kc++) {
        int k0 = kc * 32;
        f16x8 a0 = *((const f16x8*)&As[(wv * 32 + lrow) * 136 + k0 + lq * 8]);
        f16x8 a1 = *((const f16x8*)&As[(wv * 32 + 16 + lrow) * 136 + k0 + lq * 8]);
#pragma unroll
        for (int nb = 0; nb < 8; nb++) {
            f16x8 b = ((const f16x8*)wfrag)[(nb * 4 + kc) * 64 + lane];
            acc[0][nb] = __builtin_amdgcn_mfma_f32_16x16x32_f16(a0, b, acc[0][nb], 0, 0, 0);
            acc[1][nb] = __builtin_amdgcn_mfma_f32_16x16x32_f16(a1, b, acc[1][nb], 0, 0, 0);
        }
    }

#pragma unroll
    for (int ti = 0; ti < 2; ti++) {
#pragma unroll
        for (int r = 0; r < 4; r++) {
            int row = row0 + wv * 32 + ti * 16 + lq * 4 + r;
            if (row < M) {
                float dv = dinv[row];
#pragma unroll
                for (int nb = 0; nb < 8; nb++)
                    C[(size_t)row * 128 + nb * 16 + lrow] = (_Float16)(acc[ti][nb][r] * dv);
            }
        }
    }
}

// ---------------- agg1 (R7 verbatim) ----------------
__global__ __launch_bounds__(256) void agg1(const _Float16* __restrict__ hb,
                                            const int* __restrict__ srcs,
                                            const int* __restrict__ row_start,
                                            const int* __restrict__ cnt,
                                            const float* __restrict__ dinv,
                                            const float* __restrict__ bias,
                                            _Float16* __restrict__ ob, int n) {
    int node = blockIdx.x * 4 + (threadIdx.x >> 6);
    if (node >= n) return;
    int lane = threadIdx.x & 63;
    int s0 = row_start[node];
    int c = cnt[node];
    int nit = (c + 7) >> 3;
    float dn = dinv[node];
    const unsigned int* h2 = (const unsigned int*)hb;
    unsigned int hs = h2[(size_t)node * 64 + lane];
    float2 bv = ((const float2*)bias)[lane];
    float ax = 0.f, ay = 0.f, bx = 0.f, by = 0.f;
    const int4* sp = (const int4*)(srcs + s0);
    int4 sa = {}, sb = {};
    if (nit > 0) { sa = sp[0]; sb = sp[1]; }
    for (int it = 0; it < nit; it++) {
        int4 ca = sa, cb = sb;
        int nx = (it + 1 < nit) ? it + 1 : it;
        sa = sp[nx * 2]; sb = sp[nx * 2 + 1];
        unsigned int v0 = h2[(size_t)(unsigned)ca.x * 64 + lane];
        unsigned int v1 = h2[(size_t)(unsigned)ca.y * 64 + lane];
        unsigned int v2 = h2[(size_t)(unsigned)ca.z * 64 + lane];
        unsigned int v3 = h2[(size_t)(unsigned)ca.w * 64 + lane];
        unsigned int v4 = h2[(size_t)(unsigned)cb.x * 64 + lane];
        unsigned int v5 = h2[(size_t)(unsigned)cb.y * 64 + lane];
        unsigned int v6 = h2[(size_t)(unsigned)cb.z * 64 + lane];
        unsigned int v7 = h2[(size_t)(unsigned)cb.w * 64 + lane];
        ax += f16lo(v0); ay += f16hi(v0);
        bx += f16lo(v1); by += f16hi(v1);
        ax += f16lo(v2); ay += f16hi(v2);
        bx += f16lo(v3); by += f16hi(v3);
        ax += f16lo(v4); ay += f16hi(v4);
        bx += f16lo(v5); by += f16hi(v5);
        ax += f16lo(v6); ay += f16hi(v6);
        bx += f16lo(v7); by += f16hi(v7);
    }
    ax += bx + f16lo(hs);
    ay += by + f16hi(hs);
    float ox = fmaxf(fmaf(dn, ax, bv.x), 0.f) * dn;
    float oy = fmaxf(fmaf(dn, ay, bv.y), 0.f) * dn;
    ((unsigned int*)ob)[(size_t)node * 64 + lane] = pack2f16(ox, oy);
}

// ---------------- agg2 + pool (R7 verbatim) ----------------
__global__ __launch_bounds__(256) void agg2_pool(const _Float16* __restrict__ ob,
                                                 const int* __restrict__ srcs,
                                                 const int* __restrict__ row_start,
                                                 const int* __restrict__ cnt,
                                                 const float* __restrict__ dinv,
                                                 const int* __restrict__ batch,
                                                 float* __restrict__ P, int n) {
    __shared__ float red[4][128];
    int wv = threadIdx.x >> 6;
    int lane = threadIdx.x & 63;
    int base = blockIdx.x * 4;
    int node = base + wv;
    const unsigned int* h2 = (const unsigned int*)ob;
    float tx = 0.f, ty = 0.f;
    int g = -1;
    if (node < n) {
        g = batch[node];
        int s0 = row_start[node];
        int c = cnt[node];
        int nit = (c + 7) >> 3;
        float dn = dinv[node];
        unsigned int hs = h2[(size_t)node * 64 + lane];
        float ax = 0.f, ay = 0.f, bx = 0.f, by = 0.f;
        const int4* sp = (const int4*)(srcs + s0);
        int4 sa = {}, sb = {};
        if (nit > 0) { sa = sp[0]; sb = sp[1]; }
        for (int it = 0; it < nit; it++) {
            int4 ca = sa, cb = sb;
            int nx = (it + 1 < nit) ? it + 1 : it;
            sa = sp[nx * 2]; sb = sp[nx * 2 + 1];
            unsigned int v0 = h2[(size_t)(unsigned)ca.x * 64 + lane];
            unsigned int v1 = h2[(size_t)(unsigned)ca.y * 64 + lane];
            unsigned int v2 = h2[(size_t)(unsigned)ca.z * 64 + lane];
            unsigned int v3 = h2[(size_t)(unsigned)ca.w * 64 + lane];
            unsigned int v4 = h2[(size_t)(unsigned)cb.x * 64 + lane];
            unsigned int v5 = h2[(size_t)(unsigned)cb.y * 64 + lane];
            unsigned int v6 = h2[(size_t)(unsigned)cb.z * 64 + lane];
            unsigned int v7 = h2[(size_t)(unsigned)cb.w * 64 + lane];
            ax += f16lo(v0); ay += f16hi(v0);
            bx += f16lo(v1); by += f16hi(v1);
            ax += f16lo(v2); ay += f16hi(v2);
            bx += f16lo(v3); by += f16hi(v3);
            ax += f16lo(v4); ay += f16hi(v4);
            bx += f16lo(v5); by += f16hi(v5);
            ax += f16lo(v6); ay += f16hi(v6);
            bx += f16lo(v7); by += f16hi(v7);
        }
        ax += bx + f16lo(hs);
        ay += by + f16hi(hs);
        tx = dn * ax;
        ty = dn * ay;
    }
    int lastn = min(base + 3, n - 1);
    bool uniform = (base < n) && (batch[base] == batch[lastn]) && (base + 3 < n);
    if (uniform) {
        red[wv][lane * 2 + 0] = tx;
        red[wv][lane * 2 + 1] = ty;
        __syncthreads();
        if (wv == 0) {
            float sx = red[0][lane * 2] + red[1][lane * 2] + red[2][lane * 2] + red[3][lane * 2];
            float sy = red[0][lane * 2 + 1] + red[1][lane * 2 + 1] + red[2][lane * 2 + 1] + red[3][lane * 2 + 1];
            atomicAdd(&P[g * 128 + lane * 2 + 0], sx);
            atomicAdd(&P[g * 128 + lane * 2 + 1], sy);
        }
    } else if (node < n) {
        atomicAdd(&P[g * 128 + lane * 2 + 0], tx);
        atomicAdd(&P[g * 128 + lane * 2 + 1], ty);
    }
}

// ---------------- out = P @ W2 + n_g * b2 ----------------
__global__ __launch_bounds__(128) void gemm_small(const float* __restrict__ P,
                                                  const float* __restrict__ W2,
                                                  const float* __restrict__ b2,
                                                  const int* __restrict__ batch,
                                                  float* __restrict__ out, int n) {
    __shared__ float prow[128];
    int g = blockIdx.x;
    int c = threadIdx.x;
    prow[c] = P[g * 128 + c];
    __syncthreads();
    int lo = 0, hi = n;
    while (lo < hi) { int mid = (lo + hi) >> 1; if (batch[mid] < g) lo = mid + 1; else hi = mid; }
    int start = lo;
    hi = n;
    while (lo < hi) { int mid = (lo + hi) >> 1; if (batch[mid] < g + 1) lo = mid + 1; else hi = mid; }
    float ng = (float)(lo - start);
    float acc = 0.f;
#pragma unroll 8
    for (int k = 0; k < 128; k++) acc = fmaf(prow[k], W2[k * 128 + c], acc);
    out[g * 128 + c] = acc + ng * b2[c];
}

extern "C" void kernel_launch(void* const* d_in, const int* in_sizes, int n_in,
                              void* d_out, int out_size, void* d_ws, size_t ws_size,
                              hipStream_t stream) {
    const float* x  = (const float*)d_in[0];
    const int*   ei = (const int*)d_in[1];
    const int*   batch = (const int*)d_in[2];
    const float* W1 = (const float*)d_in[3];
    const float* b1 = (const float*)d_in[4];
    const float* W2 = (const float*)d_in[5];
    const float* b2 = (const float*)d_in[6];
    float* out = (float*)d_out;

    const int N = in_sizes[2];       // 50000 (assumed <= 65536)
    const int E = in_sizes[1] / 2;   // 800000
    const int G = out_size / 128;    // element count -> 128 graphs

    const int NB = (N + 255) >> 8;              // 196 buckets
    const int NBLK = (E + BCHUNK - 1) / BCHUNK; // 196 chunks
    const int ncounts = NB * NBLK;
    const int SRP = E + 7 * N + 16;             // padded srcs capacity

    // workspace layout (hb/ob have N+8 rows; row N is the sentinel zero row)
    _Float16* hb = (_Float16*)d_ws;                  // (N+8)*128 halves
    _Float16* ob = hb + (size_t)(N + 8) * 128;       // (N+8)*128 halves
    int* cnt  = (int*)(ob + (size_t)(N + 8) * 128);  // N
    int* row_start = cnt + N;                        // N
    float* dinv    = (float*)(row_start + N);        // N
    int* srcs      = (int*)(dinv + N);               // SRP
    unsigned int* bedges = (unsigned int*)(srcs + SRP); // E
    int* counts    = (int*)(bedges + E);             // NB*NBLK
    _Float16* wfrag1 = (_Float16*)(counts + ncounts);// 128*128
    float* P       = (float*)(wfrag1 + 128 * 128);   // 128*128 f32
    int* bsum      = (int*)(P + 128 * 128);          // 128

    const int nbc = (ncounts + 1023) / 1024;  // 38
    const int nbn = (N + 1023) / 1024;        // 49

    hipMemsetAsync(cnt, 0, (size_t)N * sizeof(int), stream);
    prep0<<<NBLK, 256, 0, stream>>>(ei, W1, wfrag1, P, hb, ob, cnt, counts, E, N, NB, NBLK);
    sums2<<<nbc + nbn, 256, 0, stream>>>(counts, cnt, bsum, ncounts, N, nbc);
    scan2<<<1, 128, 0, stream>>>(bsum, nbc, nbn);
    apply2<<<nbc + nbn, 256, 0, stream>>>(counts, cnt, row_start, dinv, bsum, ncounts, N, nbc);
    bin_scatter<<<NBLK, 256, 0, stream>>>(ei, counts, bedges, E, NB, NBLK);
    fill_buckets<<<NB, 256, 0, stream>>>(bedges, counts, row_start, cnt, srcs, E, N, NB, NBLK);

    gemm_mfma_f32in<<<(N + 127) / 128, 256, 0, stream>>>(x, wfrag1, dinv, hb, N);
    agg1<<<(N + 3) / 4, 256, 0, stream>>>(hb, srcs, row_start, cnt, dinv, b1, ob, N);
    agg2_pool<<<(N + 3) / 4, 256, 0, stream>>>(ob, srcs, row_start, cnt, dinv, batch, P, N);
    gemm_small<<<G, 128, 0, stream>>>(P, W2, b2, batch, out, N);
}

// Round 5
// 229.399 us; speedup vs baseline: 6.2198x; 1.0652x over previous
//
#include <hip/hip_runtime.h>
#include <hip/hip_bf16.h>

// GCN 2-layer + global_add_pool on MI355X.
// R11: preprocessing reverted to R7's proven pipeline (R10's distributed
// degree atomics were a net loss). New: "gather16" restructure of agg1 and
// agg2_pool — each lane loads dwordx4 (16B) of a row, 16-lane subgroups own
// one edge each, so one VMEM instruction fetches 4 complete rows.
// Per 8 edges: 10 VMEM -> 4 VMEM, addr VALU halved, 4x rows in flight.
// Cross-subgroup reduce = 16 shfl_xor (LDS pipe, off VMEM critical path).

typedef _Float16 f16x8 __attribute__((ext_vector_type(8)));
typedef float f32x4 __attribute__((ext_vector_type(4)));

#define BCHUNK 4096

static __device__ __forceinline__ unsigned int pack2f16(float x, float y) {
    union { unsigned short s; _Float16 h; } a, b;
    a.h = (_Float16)x; b.h = (_Float16)y;
    return (unsigned int)a.s | ((unsigned int)b.s << 16);
}

// ---------------- bucket binning (R7 verbatim) ----------------

__global__ __launch_bounds__(256) void bin_hist(const int* __restrict__ ei,
                                                int* __restrict__ counts,
                                                int E, int NB, int NBLK) {
    __shared__ int hist[256];
    int t = threadIdx.x, blk = blockIdx.x;
    for (int b = t; b < NB; b += 256) hist[b] = 0;
    __syncthreads();
    int base = blk * BCHUNK;
    int end = min(E, base + BCHUNK);
    for (int e = base + t; e < end; e += 256)
        atomicAdd(&hist[ei[E + e] >> 8], 1);
    __syncthreads();
    for (int b = t; b < NB; b += 256) counts[b * NBLK + blk] = hist[b];
}

__global__ __launch_bounds__(256) void bin_scatter(const int* __restrict__ ei,
                                                   const int* __restrict__ counts,
                                                   unsigned int* __restrict__ bedges,
                                                   int E, int NB, int NBLK) {
    __shared__ int lcur[256];
    int t = threadIdx.x, blk = blockIdx.x;
    for (int b = t; b < NB; b += 256) lcur[b] = counts[b * NBLK + blk];
    __syncthreads();
    int base = blk * BCHUNK;
    int end = min(E, base + BCHUNK);
    for (int e = base + t; e < end; e += 256) {
        int s = ei[e];
        int d = ei[E + e];
        int pos = atomicAdd(&lcur[d >> 8], 1);
        bedges[pos] = (unsigned int)s | ((unsigned int)(d & 255) << 16);
    }
}

__global__ __launch_bounds__(256) void deg_buckets(const unsigned int* __restrict__ bedges,
                                                   const int* __restrict__ counts,
                                                   int* __restrict__ cnt,
                                                   int E, int N, int NB, int NBLK) {
    __shared__ int lcnt[256];
    int b = blockIdx.x, t = threadIdx.x;
    lcnt[t] = 0;
    __syncthreads();
    int bstart = counts[b * NBLK];
    int bend = (b + 1 < NB) ? counts[(b + 1) * NBLK] : E;
    for (int i = bstart + t; i < bend; i += 256)
        atomicAdd(&lcnt[bedges[i] >> 16], 1);
    __syncthreads();
    int node = (b << 8) + t;
    if (node < N) cnt[node] = lcnt[t];
}

__global__ __launch_bounds__(256) void fill_buckets(const unsigned int* __restrict__ bedges,
                                                    const int* __restrict__ counts,
                                                    const int* __restrict__ row_start,
                                                    const int* __restrict__ cnt,
                                                    int* __restrict__ srcs,
                                                    int E, int N, int NB, int NBLK) {
    __shared__ int lcur[256];
    int b = blockIdx.x, t = threadIdx.x;
    int node = (b << 8) + t;
    lcur[t] = (node < N) ? row_start[node] : 0;
    __syncthreads();
    int bstart = counts[b * NBLK];
    int bend = (b + 1 < NB) ? counts[(b + 1) * NBLK] : E;
    for (int i = bstart + t; i < bend; i += 256) {
        unsigned int p = bedges[i];
        int pos = atomicAdd(&lcur[p >> 16], 1);
        srcs[pos] = (int)(p & 0xffffu);
    }
    if (node < N) {
        int c = cnt[node];
        int e0 = row_start[node] + c;
        int e1 = row_start[node] + ((c + 7) & ~7);
        for (int j = e0; j < e1; j++) srcs[j] = N;  // sentinel: zero row
    }
}

// ---------------- scans (R7 verbatim) ----------------

__global__ void block_sums(const int* __restrict__ data, int* __restrict__ bsum, int n) {
    __shared__ int s[256];
    int base = blockIdx.x * 1024;
    int t = threadIdx.x;
    int v = 0;
#pragma unroll
    for (int i = 0; i < 4; i++) {
        int idx = base + t * 4 + i;
        if (idx < n) v += data[idx];
    }
    s[t] = v;
    __syncthreads();
    for (int off = 128; off > 0; off >>= 1) {
        if (t < off) s[t] += s[t + off];
        __syncthreads();
    }
    if (t == 0) bsum[blockIdx.x] = s[0];
}

__global__ void block_sums_pad(const int* __restrict__ data, int* __restrict__ bsum, int n) {
    __shared__ int s[256];
    int base = blockIdx.x * 1024;
    int t = threadIdx.x;
    int v = 0;
#pragma unroll
    for (int i = 0; i < 4; i++) {
        int idx = base + t * 4 + i;
        if (idx < n) v += (data[idx] + 7) & ~7;
    }
    s[t] = v;
    __syncthreads();
    for (int off = 128; off > 0; off >>= 1) {
        if (t < off) s[t] += s[t + off];
        __syncthreads();
    }
    if (t == 0) bsum[blockIdx.x] = s[0];
}

__global__ void scan_bsum(int* __restrict__ bsum, int nb) {
    int lane = threadIdx.x & 63;
    int v = (lane < nb) ? bsum[lane] : 0;
    int incl = v;
#pragma unroll
    for (int off = 1; off < 64; off *= 2) {
        int u = __shfl_up(incl, off);
        if (lane >= off) incl += u;
    }
    if (lane < nb) bsum[lane] = incl - v;  // exclusive
}

__global__ void scan_apply(int* __restrict__ data, const int* __restrict__ bsum, int n) {
    __shared__ int s[256];
    int base = blockIdx.x * 1024;
    int t = threadIdx.x;
    int loc[4];
    int v = 0;
#pragma unroll
    for (int i = 0; i < 4; i++) {
        int idx = base + t * 4 + i;
        loc[i] = (idx < n) ? data[idx] : 0;
        v += loc[i];
    }
    s[t] = v;
    __syncthreads();
    for (int off = 1; off < 256; off *= 2) {
        int u = (t >= off) ? s[t - off] : 0;
        __syncthreads();
        s[t] += u;
        __syncthreads();
    }
    int excl = s[t] - v + bsum[blockIdx.x];
#pragma unroll
    for (int i = 0; i < 4; i++) {
        int idx = base + t * 4 + i;
        if (idx < n) { data[idx] = excl; excl += loc[i]; }
    }
}

__global__ void scan_nodes(const int* __restrict__ cnt, const int* __restrict__ bsum,
                           int* __restrict__ row_start, float* __restrict__ dinv, int n) {
    __shared__ int s[256];
    int base = blockIdx.x * 1024;
    int t = threadIdx.x;
    int loc[4], pc[4];
    int v = 0;
#pragma unroll
    for (int i = 0; i < 4; i++) {
        int idx = base + t * 4 + i;
        loc[i] = (idx < n) ? cnt[idx] : 0;
        pc[i] = (loc[i] + 7) & ~7;
        v += pc[i];
    }
    s[t] = v;
    __syncthreads();
    for (int off = 1; off < 256; off *= 2) {
        int u = (t >= off) ? s[t - off] : 0;
        __syncthreads();
        s[t] += u;
        __syncthreads();
    }
    int excl = s[t] - v + bsum[blockIdx.x];
#pragma unroll
    for (int i = 0; i < 4; i++) {
        int idx = base + t * 4 + i;
        if (idx < n) {
            row_start[idx] = excl;
            dinv[idx] = rsqrtf((float)loc[i] + 1.0f);
            excl += pc[i];
        }
    }
}

// ---------------- W fragment prep ----------------
__global__ void wprep(const float* __restrict__ W, _Float16* __restrict__ wfrag) {
    int idx = blockIdx.x * 256 + threadIdx.x;  // 2048 total
    if (idx >= 2048) return;
    int lane = idx & 63;
    int kc = (idx >> 6) & 3;
    int nb = idx >> 8;
    int col = nb * 16 + (lane & 15);
    int krow = kc * 32 + (lane >> 4) * 8;
#pragma unroll
    for (int j = 0; j < 8; j++)
        wfrag[idx * 8 + j] = (_Float16)W[(krow + j) * 128 + col];
}

// ---------------- GEMM: C = dinv[row] * (A @ W), fp16 MFMA ----------------
__global__ __launch_bounds__(256) void gemm_mfma_f32in(const float* __restrict__ A,
                                                       const _Float16* __restrict__ wfrag,
                                                       const float* __restrict__ dinv,
                                                       _Float16* __restrict__ C, int M) {
    __shared__ _Float16 As[128 * 136];
    int t = threadIdx.x;
    int row0 = blockIdx.x * 128;

    const float4* A4 = (const float4*)A;
#pragma unroll
    for (int it = 0; it < 16; it++) {
        int v = it * 256 + t;
        int row = v >> 5;
        int seg = v & 31;
        float4 val = make_float4(0.f, 0.f, 0.f, 0.f);
        if (row0 + row < M) val = A4[(size_t)(row0 + row) * 32 + seg];
        _Float16* pp = &As[row * 136 + seg * 4];
        pp[0] = (_Float16)val.x; pp[1] = (_Float16)val.y;
        pp[2] = (_Float16)val.z; pp[3] = (_Float16)val.w;
    }
    __syncthreads();

    int wv = t >> 6;
    int lane = t & 63;
    int lrow = lane & 15;
    int lq = lane >> 4;

    f32x4 acc[2][8];
#pragma unroll
    for (int i = 0; i < 2; i++)
#pragma unroll
        for (int j = 0; j < 8; j++) acc[i][j] = (f32x4){0.f, 0.f, 0.f, 0.f};

#pragma unroll
    for (int kc = 0; kc < 4; kc++) {
        int k0 = kc * 32;
        f16x8 a0 = *((const f16x8*)&As[(wv * 32 + lrow) * 136 + k0 + lq * 8]);
        f16x8 a1 = *((const f16x8*)&As[(wv * 32 + 16 + lrow) * 136 + k0 + lq * 8]);
#pragma unroll
        for (int nb = 0; nb < 8; nb++) {
            f16x8 b = ((const f16x8*)wfrag)[(nb * 4 + kc) * 64 + lane];
            acc[0][nb] = __builtin_amdgcn_mfma_f32_16x16x32_f16(a0, b, acc[0][nb], 0, 0, 0);
            acc[1][nb] = __builtin_amdgcn_mfma_f32_16x16x32_f16(a1, b, acc[1][nb], 0, 0, 0);
        }
    }

#pragma unroll
    for (int ti = 0; ti < 2; ti++) {
#pragma unroll
        for (int r = 0; r < 4; r++) {
            int row = row0 + wv * 32 + ti * 16 + lq * 4 + r;
            if (row < M) {
                float dv = dinv[row];
#pragma unroll
                for (int nb = 0; nb < 8; nb++)
                    C[(size_t)row * 128 + nb * 16 + lrow] = (_Float16)(acc[ti][nb][r] * dv);
            }
        }
    }
}

// ---------------- agg1 (gather16): o = relu(dn*(sum+self)+b1); ob = dn*o ----------------
// lane = sg*16 + cc: subgroup sg (0..3) owns edges e ≡ sg (mod 4),
// chunk cc owns halves [cc*8, cc*8+8) of the 128-wide row.
// One dwordx4 load fetches 16B of a row; one instruction = 4 full rows.
__global__ __launch_bounds__(256) void agg1(const _Float16* __restrict__ hb,
                                            const int* __restrict__ srcs,
                                            const int* __restrict__ row_start,
                                            const int* __restrict__ cnt,
                                            const float* __restrict__ dinv,
                                            const float* __restrict__ bias,
                                            _Float16* __restrict__ ob, int n) {
    int node = blockIdx.x * 4 + (threadIdx.x >> 6);
    if (node >= n) return;
    int lane = threadIdx.x & 63;
    int cc = lane & 15;
    int sg = lane >> 4;
    int s0 = row_start[node];
    int c = cnt[node];
    int nit = (c + 7) >> 3;   // 8 edges per iteration (pad8 guaranteed)
    float dn = dinv[node];

    float acc[8];
#pragma unroll
    for (int j = 0; j < 8; j++) acc[j] = 0.f;

    const int* sp = srcs + s0;
    int i0 = 0, i1 = 0;
    if (nit > 0) { i0 = sp[sg]; i1 = sp[4 + sg]; }
    for (int it = 0; it < nit; it++) {
        int cs0 = i0, cs1 = i1;
        int nxt = (it + 1 < nit) ? (it + 1) : it;    // branchless prefetch
        i0 = sp[nxt * 8 + sg]; i1 = sp[nxt * 8 + 4 + sg];
        f16x8 v0 = *((const f16x8*)&hb[(size_t)(unsigned)cs0 * 128 + cc * 8]);
        f16x8 v1 = *((const f16x8*)&hb[(size_t)(unsigned)cs1 * 128 + cc * 8]);
#pragma unroll
        for (int j = 0; j < 8; j++) acc[j] += (float)v0[j];
#pragma unroll
        for (int j = 0; j < 8; j++) acc[j] += (float)v1[j];
    }
    // reduce across the 4 subgroups (lanes xor 16, 32)
#pragma unroll
    for (int j = 0; j < 8; j++) {
        acc[j] += __shfl_xor(acc[j], 16);
        acc[j] += __shfl_xor(acc[j], 32);
    }
    // self + bias + relu + pre-scale
    f16x8 hs = *((const f16x8*)&hb[(size_t)node * 128 + cc * 8]);
    float4 b0 = ((const float4*)bias)[cc * 2];
    float4 b1v = ((const float4*)bias)[cc * 2 + 1];
    float bb[8] = {b0.x, b0.y, b0.z, b0.w, b1v.x, b1v.y, b1v.z, b1v.w};
    f16x8 o;
#pragma unroll
    for (int j = 0; j < 8; j++) {
        float tv = acc[j] + (float)hs[j];
        tv = fmaxf(fmaf(dn, tv, bb[j]), 0.f) * dn;
        o[j] = (_Float16)tv;
    }
    if (sg == 0) *((f16x8*)&ob[(size_t)node * 128 + cc * 8]) = o;
}

// ---------------- agg2 + pool (gather16) ----------------
__global__ __launch_bounds__(256) void agg2_pool(const _Float16* __restrict__ ob,
                                                 const int* __restrict__ srcs,
                                                 const int* __restrict__ row_start,
                                                 const int* __restrict__ cnt,
                                                 const float* __restrict__ dinv,
                                                 const int* __restrict__ batch,
                                                 float* __restrict__ P, int n) {
    __shared__ float red[4][128];
    int wv = threadIdx.x >> 6;
    int lane = threadIdx.x & 63;
    int cc = lane & 15;
    int sg = lane >> 4;
    int base = blockIdx.x * 4;
    int node = base + wv;

    float t8[8];
#pragma unroll
    for (int j = 0; j < 8; j++) t8[j] = 0.f;
    int g = -1;

    if (node < n) {
        g = batch[node];
        int s0 = row_start[node];
        int c = cnt[node];
        int nit = (c + 7) >> 3;
        float dn = dinv[node];

        float acc[8];
#pragma unroll
        for (int j = 0; j < 8; j++) acc[j] = 0.f;
        const int* sp = srcs + s0;
        int i0 = 0, i1 = 0;
        if (nit > 0) { i0 = sp[sg]; i1 = sp[4 + sg]; }
        for (int it = 0; it < nit; it++) {
            int cs0 = i0, cs1 = i1;
            int nxt = (it + 1 < nit) ? (it + 1) : it;
            i0 = sp[nxt * 8 + sg]; i1 = sp[nxt * 8 + 4 + sg];
            f16x8 v0 = *((const f16x8*)&ob[(size_t)(unsigned)cs0 * 128 + cc * 8]);
            f16x8 v1 = *((const f16x8*)&ob[(size_t)(unsigned)cs1 * 128 + cc * 8]);
#pragma unroll
            for (int j = 0; j < 8; j++) acc[j] += (float)v0[j];
#pragma unroll
            for (int j = 0; j < 8; j++) acc[j] += (float)v1[j];
        }
#pragma unroll
        for (int j = 0; j < 8; j++) {
            acc[j] += __shfl_xor(acc[j], 16);
            acc[j] += __shfl_xor(acc[j], 32);
        }
        f16x8 hs = *((const f16x8*)&ob[(size_t)node * 128 + cc * 8]);
#pragma unroll
        for (int j = 0; j < 8; j++) t8[j] = dn * (acc[j] + (float)hs[j]);
    }

    int lastn = min(base + 3, n - 1);
    bool uniform = (base < n) && (batch[base] == batch[lastn]) && (base + 3 < n);
    if (uniform) {
        if (sg == 0) {
#pragma unroll
            for (int j = 0; j < 8; j++) red[wv][cc * 8 + j] = t8[j];
        }
        __syncthreads();
        if (wv == 0) {
            int col = lane * 2;
            float sx = red[0][col] + red[1][col] + red[2][col] + red[3][col];
            float sy = red[0][col + 1] + red[1][col + 1] + red[2][col + 1] + red[3][col + 1];
            atomicAdd(&P[g * 128 + col], sx);
            atomicAdd(&P[g * 128 + col + 1], sy);
        }
    } else if (node < n) {
        if (sg == 0) {
#pragma unroll
            for (int j = 0; j < 8; j++) atomicAdd(&P[g * 128 + cc * 8 + j], t8[j]);
        }
    }
}

// ---------------- out = P @ W2 + n_g * b2 ----------------
__global__ __launch_bounds__(128) void gemm_small(const float* __restrict__ P,
                                                  const float* __restrict__ W2,
                                                  const float* __restrict__ b2,
                                                  const int* __restrict__ batch,
                                                  float* __restrict__ out, int n) {
    __shared__ float prow[128];
    int g = blockIdx.x;
    int c = threadIdx.x;
    prow[c] = P[g * 128 + c];
    __syncthreads();
    int lo = 0, hi = n;
    while (lo < hi) { int mid = (lo + hi) >> 1; if (batch[mid] < g) lo = mid + 1; else hi = mid; }
    int start = lo;
    hi = n;
    while (lo < hi) { int mid = (lo + hi) >> 1; if (batch[mid] < g + 1) lo = mid + 1; else hi = mid; }
    float ng = (float)(lo - start);
    float acc = 0.f;
#pragma unroll 8
    for (int k = 0; k < 128; k++) acc = fmaf(prow[k], W2[k * 128 + c], acc);
    out[g * 128 + c] = acc + ng * b2[c];
}

extern "C" void kernel_launch(void* const* d_in, const int* in_sizes, int n_in,
                              void* d_out, int out_size, void* d_ws, size_t ws_size,
                              hipStream_t stream) {
    const float* x  = (const float*)d_in[0];
    const int*   ei = (const int*)d_in[1];
    const int*   batch = (const int*)d_in[2];
    const float* W1 = (const float*)d_in[3];
    const float* b1 = (const float*)d_in[4];
    const float* W2 = (const float*)d_in[5];
    const float* b2 = (const float*)d_in[6];
    float* out = (float*)d_out;

    const int N = in_sizes[2];       // 50000 (assumed <= 65536)
    const int E = in_sizes[1] / 2;   // 800000
    const int G = out_size / 128;    // element count -> 128 graphs

    const int NB = (N + 255) >> 8;              // 196 buckets
    const int NBLK = (E + BCHUNK - 1) / BCHUNK; // 196 chunks
    const int ncounts = NB * NBLK;
    const int SRP = E + 7 * N + 16;             // padded srcs capacity

    // workspace layout (hb/ob have N+8 rows; row N is the sentinel zero row)
    _Float16* hb = (_Float16*)d_ws;                  // (N+8)*128 halves
    _Float16* ob = hb + (size_t)(N + 8) * 128;       // (N+8)*128 halves
    int* cnt  = (int*)(ob + (size_t)(N + 8) * 128);  // N
    int* row_start = cnt + N;                        // N
    float* dinv    = (float*)(row_start + N);        // N
    int* srcs      = (int*)(dinv + N);               // SRP
    unsigned int* bedges = (unsigned int*)(srcs + SRP); // E
    int* counts    = (int*)(bedges + E);             // NB*NBLK
    _Float16* wfrag1 = (_Float16*)(counts + ncounts);// 128*128
    float* P       = (float*)(wfrag1 + 128 * 128);   // 128*128 f32
    int* bsum      = (int*)(P + 128 * 128);          // <=64

    const int nbc = (ncounts + 1023) / 1024;  // <=64
    const int nbn = (N + 1023) / 1024;        // <=64

    hipMemsetAsync(P, 0, 128 * 128 * sizeof(float), stream);
    hipMemsetAsync(hb + (size_t)N * 128, 0, 128 * sizeof(_Float16), stream);
    hipMemsetAsync(ob + (size_t)N * 128, 0, 128 * sizeof(_Float16), stream);
    wprep<<<8, 256, 0, stream>>>(W1, wfrag1);

    bin_hist<<<NBLK, 256, 0, stream>>>(ei, counts, E, NB, NBLK);
    block_sums<<<nbc, 256, 0, stream>>>(counts, bsum, ncounts);
    scan_bsum<<<1, 64, 0, stream>>>(bsum, nbc);
    scan_apply<<<nbc, 256, 0, stream>>>(counts, bsum, ncounts);
    bin_scatter<<<NBLK, 256, 0, stream>>>(ei, counts, bedges, E, NB, NBLK);
    deg_buckets<<<NB, 256, 0, stream>>>(bedges, counts, cnt, E, N, NB, NBLK);
    block_sums_pad<<<nbn, 256, 0, stream>>>(cnt, bsum, N);
    scan_bsum<<<1, 64, 0, stream>>>(bsum, nbn);
    scan_nodes<<<nbn, 256, 0, stream>>>(cnt, bsum, row_start, dinv, N);
    fill_buckets<<<NB, 256, 0, stream>>>(bedges, counts, row_start, cnt, srcs, E, N, NB, NBLK);

    gemm_mfma_f32in<<<(N + 127) / 128, 256, 0, stream>>>(x, wfrag1, dinv, hb, N);
    agg1<<<(N + 3) / 4, 256, 0, stream>>>(hb, srcs, row_start, cnt, dinv, b1, ob, N);
    agg2_pool<<<(N + 3) / 4, 256, 0, stream>>>(ob, srcs, row_start, cnt, dinv, batch, P, N);
    gemm_small<<<G, 128, 0, stream>>>(P, W2, b2, batch, out, N);
}

// Round 7
// 223.259 us; speedup vs baseline: 6.3908x; 1.0275x over previous
//
#include <hip/hip_runtime.h>
#include <hip/hip_bf16.h>

// GCN 2-layer + global_add_pool on MI355X.
// R13: R12's container failure was ambiguous (infra vs lookback-scan hang).
// Keep only the hazard-free half of R12: bin_hist phase-0 absorbs the 3
// memsets + wprep (independent writes, ordinary launch). Scans revert to
// the R7-proven 3-kernel chains (no cross-block spin-poll). 18 queue ops
// -> 14. All other kernels verbatim from R11 (gather16 aggs, MFMA gemm).

typedef _Float16 f16x8 __attribute__((ext_vector_type(8)));
typedef float f32x4 __attribute__((ext_vector_type(4)));

#define BCHUNK 4096

// ---------------- bin_hist + phase-0 init ----------------
__global__ __launch_bounds__(256) void bin_hist(const int* __restrict__ ei,
                                                const float* __restrict__ W1,
                                                _Float16* __restrict__ wfrag,
                                                float* __restrict__ P,
                                                _Float16* __restrict__ hb,
                                                _Float16* __restrict__ ob,
                                                int* __restrict__ counts,
                                                int E, int N, int NB, int NBLK) {
    __shared__ int hist[256];
    int t = threadIdx.x, blk = blockIdx.x;
    int gtid = blk * 256 + t;
    int gstride = gridDim.x * 256;

    // phase 0: independent init (P, sentinel rows, wfrag) — no grid deps
    for (int i = gtid; i < 128 * 128; i += gstride) P[i] = 0.f;
    if (gtid < 64) {
        ((unsigned int*)(hb + (size_t)N * 128))[gtid] = 0u;
        ((unsigned int*)(ob + (size_t)N * 128))[gtid] = 0u;
    }
    if (gtid < 2048) {
        int lane = gtid & 63, kc = (gtid >> 6) & 3, nb = gtid >> 8;
        int col = nb * 16 + (lane & 15);
        int krow = kc * 32 + (lane >> 4) * 8;
#pragma unroll
        for (int j = 0; j < 8; j++)
            wfrag[gtid * 8 + j] = (_Float16)W1[(krow + j) * 128 + col];
    }

    // bucket histogram
    for (int b = t; b < NB; b += 256) hist[b] = 0;
    __syncthreads();
    int base = blk * BCHUNK;
    int end = min(E, base + BCHUNK);
    for (int e = base + t; e < end; e += 256)
        atomicAdd(&hist[ei[E + e] >> 8], 1);
    __syncthreads();
    for (int b = t; b < NB; b += 256) counts[b * NBLK + blk] = hist[b];
}

// ---------------- scans (R7-proven) ----------------

__global__ void block_sums(const int* __restrict__ data, int* __restrict__ bsum, int n) {
    __shared__ int s[256];
    int base = blockIdx.x * 1024;
    int t = threadIdx.x;
    int v = 0;
#pragma unroll
    for (int i = 0; i < 4; i++) {
        int idx = base + t * 4 + i;
        if (idx < n) v += data[idx];
    }
    s[t] = v;
    __syncthreads();
    for (int off = 128; off > 0; off >>= 1) {
        if (t < off) s[t] += s[t + off];
        __syncthreads();
    }
    if (t == 0) bsum[blockIdx.x] = s[0];
}

__global__ void block_sums_pad(const int* __restrict__ data, int* __restrict__ bsum, int n) {
    __shared__ int s[256];
    int base = blockIdx.x * 1024;
    int t = threadIdx.x;
    int v = 0;
#pragma unroll
    for (int i = 0; i < 4; i++) {
        int idx = base + t * 4 + i;
        if (idx < n) v += (data[idx] + 7) & ~7;
    }
    s[t] = v;
    __syncthreads();
    for (int off = 128; off > 0; off >>= 1) {
        if (t < off) s[t] += s[t + off];
        __syncthreads();
    }
    if (t == 0) bsum[blockIdx.x] = s[0];
}

__global__ void scan_bsum(int* __restrict__ bsum, int nb) {
    int lane = threadIdx.x & 63;
    int v = (lane < nb) ? bsum[lane] : 0;
    int incl = v;
#pragma unroll
    for (int off = 1; off < 64; off *= 2) {
        int u = __shfl_up(incl, off);
        if (lane >= off) incl += u;
    }
    if (lane < nb) bsum[lane] = incl - v;  // exclusive
}

__global__ void scan_apply(int* __restrict__ data, const int* __restrict__ bsum, int n) {
    __shared__ int s[256];
    int base = blockIdx.x * 1024;
    int t = threadIdx.x;
    int loc[4];
    int v = 0;
#pragma unroll
    for (int i = 0; i < 4; i++) {
        int idx = base + t * 4 + i;
        loc[i] = (idx < n) ? data[idx] : 0;
        v += loc[i];
    }
    s[t] = v;
    __syncthreads();
    for (int off = 1; off < 256; off *= 2) {
        int u = (t >= off) ? s[t - off] : 0;
        __syncthreads();
        s[t] += u;
        __syncthreads();
    }
    int excl = s[t] - v + bsum[blockIdx.x];
#pragma unroll
    for (int i = 0; i < 4; i++) {
        int idx = base + t * 4 + i;
        if (idx < n) { data[idx] = excl; excl += loc[i]; }
    }
}

__global__ void scan_nodes(const int* __restrict__ cnt, const int* __restrict__ bsum,
                           int* __restrict__ row_start, float* __restrict__ dinv, int n) {
    __shared__ int s[256];
    int base = blockIdx.x * 1024;
    int t = threadIdx.x;
    int loc[4], pc[4];
    int v = 0;
#pragma unroll
    for (int i = 0; i < 4; i++) {
        int idx = base + t * 4 + i;
        loc[i] = (idx < n) ? cnt[idx] : 0;
        pc[i] = (loc[i] + 7) & ~7;
        v += pc[i];
    }
    s[t] = v;
    __syncthreads();
    for (int off = 1; off < 256; off *= 2) {
        int u = (t >= off) ? s[t - off] : 0;
        __syncthreads();
        s[t] += u;
        __syncthreads();
    }
    int excl = s[t] - v + bsum[blockIdx.x];
#pragma unroll
    for (int i = 0; i < 4; i++) {
        int idx = base + t * 4 + i;
        if (idx < n) {
            row_start[idx] = excl;
            dinv[idx] = rsqrtf((float)loc[i] + 1.0f);
            excl += pc[i];
        }
    }
}

// ---------------- bin_scatter / deg_buckets / fill_buckets (verbatim) ----------------

__global__ __launch_bounds__(256) void bin_scatter(const int* __restrict__ ei,
                                                   const int* __restrict__ counts,
                                                   unsigned int* __restrict__ bedges,
                                                   int E, int NB, int NBLK) {
    __shared__ int lcur[256];
    int t = threadIdx.x, blk = blockIdx.x;
    for (int b = t; b < NB; b += 256) lcur[b] = counts[b * NBLK + blk];
    __syncthreads();
    int base = blk * BCHUNK;
    int end = min(E, base + BCHUNK);
    for (int e = base + t; e < end; e += 256) {
        int s = ei[e];
        int d = ei[E + e];
        int pos = atomicAdd(&lcur[d >> 8], 1);
        bedges[pos] = (unsigned int)s | ((unsigned int)(d & 255) << 16);
    }
}

__global__ __launch_bounds__(256) void deg_buckets(const unsigned int* __restrict__ bedges,
                                                   const int* __restrict__ counts,
                                                   int* __restrict__ cnt,
                                                   int E, int N, int NB, int NBLK) {
    __shared__ int lcnt[256];
    int b = blockIdx.x, t = threadIdx.x;
    lcnt[t] = 0;
    __syncthreads();
    int bstart = counts[b * NBLK];
    int bend = (b + 1 < NB) ? counts[(b + 1) * NBLK] : E;
    for (int i = bstart + t; i < bend; i += 256)
        atomicAdd(&lcnt[bedges[i] >> 16], 1);
    __syncthreads();
    int node = (b << 8) + t;
    if (node < N) cnt[node] = lcnt[t];
}

__global__ __launch_bounds__(256) void fill_buckets(const unsigned int* __restrict__ bedges,
                                                    const int* __restrict__ counts,
                                                    const int* __restrict__ row_start,
                                                    const int* __restrict__ cnt,
                                                    int* __restrict__ srcs,
                                                    int E, int N, int NB, int NBLK) {
    __shared__ int lcur[256];
    int b = blockIdx.x, t = threadIdx.x;
    int node = (b << 8) + t;
    lcur[t] = (node < N) ? row_start[node] : 0;
    __syncthreads();
    int bstart = counts[b * NBLK];
    int bend = (b + 1 < NB) ? counts[(b + 1) * NBLK] : E;
    for (int i = bstart + t; i < bend; i += 256) {
        unsigned int p = bedges[i];
        int pos = atomicAdd(&lcur[p >> 16], 1);
        srcs[pos] = (int)(p & 0xffffu);
    }
    if (node < N) {
        int c = cnt[node];
        int e0 = row_start[node] + c;
        int e1 = row_start[node] + ((c + 7) & ~7);
        for (int j = e0; j < e1; j++) srcs[j] = N;  // sentinel: zero row
    }
}

// ---------------- GEMM: C = dinv[row] * (A @ W), fp16 MFMA (verbatim) ----------------
__global__ __launch_bounds__(256) void gemm_mfma_f32in(const float* __restrict__ A,
                                                       const _Float16* __restrict__ wfrag,
                                                       const float* __restrict__ dinv,
                                                       _Float16* __restrict__ C, int M) {
    __shared__ _Float16 As[128 * 136];
    int t = threadIdx.x;
    int row0 = blockIdx.x * 128;

    const float4* A4 = (const float4*)A;
#pragma unroll
    for (int it = 0; it < 16; it++) {
        int v = it * 256 + t;
        int row = v >> 5;
        int seg = v & 31;
        float4 val = make_float4(0.f, 0.f, 0.f, 0.f);
        if (row0 + row < M) val = A4[(size_t)(row0 + row) * 32 + seg];
        _Float16* pp = &As[row * 136 + seg * 4];
        pp[0] = (_Float16)val.x; pp[1] = (_Float16)val.y;
        pp[2] = (_Float16)val.z; pp[3] = (_Float16)val.w;
    }
    __syncthreads();

    int wv = t >> 6;
    int lane = t & 63;
    int lrow = lane & 15;
    int lq = lane >> 4;

    f32x4 acc[2][8];
#pragma unroll
    for (int i = 0; i < 2; i++)
#pragma unroll
        for (int j = 0; j < 8; j++) acc[i][j] = (f32x4){0.f, 0.f, 0.f, 0.f};

#pragma unroll
    for (int kc = 0; kc < 4; kc++) {
        int k0 = kc * 32;
        f16x8 a0 = *((const f16x8*)&As[(wv * 32 + lrow) * 136 + k0 + lq * 8]);
        f16x8 a1 = *((const f16x8*)&As[(wv * 32 + 16 + lrow) * 136 + k0 + lq * 8]);
#pragma unroll
        for (int nb = 0; nb < 8; nb++) {
            f16x8 b = ((const f16x8*)wfrag)[(nb * 4 + kc) * 64 + lane];
            acc[0][nb] = __builtin_amdgcn_mfma_f32_16x16x32_f16(a0, b, acc[0][nb], 0, 0, 0);
            acc[1][nb] = __builtin_amdgcn_mfma_f32_16x16x32_f16(a1, b, acc[1][nb], 0, 0, 0);
        }
    }

#pragma unroll
    for (int ti = 0; ti < 2; ti++) {
#pragma unroll
        for (int r = 0; r < 4; r++) {
            int row = row0 + wv * 32 + ti * 16 + lq * 4 + r;
            if (row < M) {
                float dv = dinv[row];
#pragma unroll
                for (int nb = 0; nb < 8; nb++)
                    C[(size_t)row * 128 + nb * 16 + lrow] = (_Float16)(acc[ti][nb][r] * dv);
            }
        }
    }
}

// ---------------- agg1 (gather16, verbatim) ----------------
__global__ __launch_bounds__(256) void agg1(const _Float16* __restrict__ hb,
                                            const int* __restrict__ srcs,
                                            const int* __restrict__ row_start,
                                            const int* __restrict__ cnt,
                                            const float* __restrict__ dinv,
                                            const float* __restrict__ bias,
                                            _Float16* __restrict__ ob, int n) {
    int node = blockIdx.x * 4 + (threadIdx.x >> 6);
    if (node >= n) return;
    int lane = threadIdx.x & 63;
    int cc = lane & 15;
    int sg = lane >> 4;
    int s0 = row_start[node];
    int c = cnt[node];
    int nit = (c + 7) >> 3;
    float dn = dinv[node];

    float acc[8];
#pragma unroll
    for (int j = 0; j < 8; j++) acc[j] = 0.f;

    const int* sp = srcs + s0;
    int i0 = 0, i1 = 0;
    if (nit > 0) { i0 = sp[sg]; i1 = sp[4 + sg]; }
    for (int it = 0; it < nit; it++) {
        int cs0 = i0, cs1 = i1;
        int nxt = (it + 1 < nit) ? (it + 1) : it;
        i0 = sp[nxt * 8 + sg]; i1 = sp[nxt * 8 + 4 + sg];
        f16x8 v0 = *((const f16x8*)&hb[(size_t)(unsigned)cs0 * 128 + cc * 8]);
        f16x8 v1 = *((const f16x8*)&hb[(size_t)(unsigned)cs1 * 128 + cc * 8]);
#pragma unroll
        for (int j = 0; j < 8; j++) acc[j] += (float)v0[j];
#pragma unroll
        for (int j = 0; j < 8; j++) acc[j] += (float)v1[j];
    }
#pragma unroll
    for (int j = 0; j < 8; j++) {
        acc[j] += __shfl_xor(acc[j], 16);
        acc[j] += __shfl_xor(acc[j], 32);
    }
    f16x8 hs = *((const f16x8*)&hb[(size_t)node * 128 + cc * 8]);
    float4 b0 = ((const float4*)bias)[cc * 2];
    float4 b1v = ((const float4*)bias)[cc * 2 + 1];
    float bb[8] = {b0.x, b0.y, b0.z, b0.w, b1v.x, b1v.y, b1v.z, b1v.w};
    f16x8 o;
#pragma unroll
    for (int j = 0; j < 8; j++) {
        float tv = acc[j] + (float)hs[j];
        tv = fmaxf(fmaf(dn, tv, bb[j]), 0.f) * dn;
        o[j] = (_Float16)tv;
    }
    if (sg == 0) *((f16x8*)&ob[(size_t)node * 128 + cc * 8]) = o;
}

// ---------------- agg2 + pool (gather16, verbatim) ----------------
__global__ __launch_bounds__(256) void agg2_pool(const _Float16* __restrict__ ob,
                                                 const int* __restrict__ srcs,
                                                 const int* __restrict__ row_start,
                                                 const int* __restrict__ cnt,
                                                 const float* __restrict__ dinv,
                                                 const int* __restrict__ batch,
                                                 float* __restrict__ P, int n) {
    __shared__ float red[4][128];
    int wv = threadIdx.x >> 6;
    int lane = threadIdx.x & 63;
    int cc = lane & 15;
    int sg = lane >> 4;
    int base = blockIdx.x * 4;
    int node = base + wv;

    float t8[8];
#pragma unroll
    for (int j = 0; j < 8; j++) t8[j] = 0.f;
    int g = -1;

    if (node < n) {
        g = batch[node];
        int s0 = row_start[node];
        int c = cnt[node];
        int nit = (c + 7) >> 3;
        float dn = dinv[node];

        float acc[8];
#pragma unroll
        for (int j = 0; j < 8; j++) acc[j] = 0.f;
        const int* sp = srcs + s0;
        int i0 = 0, i1 = 0;
        if (nit > 0) { i0 = sp[sg]; i1 = sp[4 + sg]; }
        for (int it = 0; it < nit; it++) {
            int cs0 = i0, cs1 = i1;
            int nxt = (it + 1 < nit) ? (it + 1) : it;
            i0 = sp[nxt * 8 + sg]; i1 = sp[nxt * 8 + 4 + sg];
            f16x8 v0 = *((const f16x8*)&ob[(size_t)(unsigned)cs0 * 128 + cc * 8]);
            f16x8 v1 = *((const f16x8*)&ob[(size_t)(unsigned)cs1 * 128 + cc * 8]);
#pragma unroll
            for (int j = 0; j < 8; j++) acc[j] += (float)v0[j];
#pragma unroll
            for (int j = 0; j < 8; j++) acc[j] += (float)v1[j];
        }
#pragma unroll
        for (int j = 0; j < 8; j++) {
            acc[j] += __shfl_xor(acc[j], 16);
            acc[j] += __shfl_xor(acc[j], 32);
        }
        f16x8 hs = *((const f16x8*)&ob[(size_t)node * 128 + cc * 8]);
#pragma unroll
        for (int j = 0; j < 8; j++) t8[j] = dn * (acc[j] + (float)hs[j]);
    }

    int lastn = min(base + 3, n - 1);
    bool uniform = (base < n) && (batch[base] == batch[lastn]) && (base + 3 < n);
    if (uniform) {
        if (sg == 0) {
#pragma unroll
            for (int j = 0; j < 8; j++) red[wv][cc * 8 + j] = t8[j];
        }
        __syncthreads();
        if (wv == 0) {
            int col = lane * 2;
            float sx = red[0][col] + red[1][col] + red[2][col] + red[3][col];
            float sy = red[0][col + 1] + red[1][col + 1] + red[2][col + 1] + red[3][col + 1];
            atomicAdd(&P[g * 128 + col], sx);
            atomicAdd(&P[g * 128 + col + 1], sy);
        }
    } else if (node < n) {
        if (sg == 0) {
#pragma unroll
            for (int j = 0; j < 8; j++) atomicAdd(&P[g * 128 + cc * 8 + j], t8[j]);
        }
    }
}

// ---------------- out = P @ W2 + n_g * b2 (verbatim) ----------------
__global__ __launch_bounds__(128) void gemm_small(const float* __restrict__ P,
                                                  const float* __restrict__ W2,
                                                  const float* __restrict__ b2,
                                                  const int* __restrict__ batch,
                                                  float* __restrict__ out, int n) {
    __shared__ float prow[128];
    int g = blockIdx.x;
    int c = threadIdx.x;
    prow[c] = P[g * 128 + c];
    __syncthreads();
    int lo = 0, hi = n;
    while (lo < hi) { int mid = (lo + hi) >> 1; if (batch[mid] < g) lo = mid + 1; else hi = mid; }
    int start = lo;
    hi = n;
    while (lo < hi) { int mid = (lo + hi) >> 1; if (batch[mid] < g + 1) lo = mid + 1; else hi = mid; }
    float ng = (float)(lo - start);
    float acc = 0.f;
#pragma unroll 8
    for (int k = 0; k < 128; k++) acc = fmaf(prow[k], W2[k * 128 + c], acc);
    out[g * 128 + c] = acc + ng * b2[c];
}

extern "C" void kernel_launch(void* const* d_in, const int* in_sizes, int n_in,
                              void* d_out, int out_size, void* d_ws, size_t ws_size,
                              hipStream_t stream) {
    const float* x  = (const float*)d_in[0];
    const int*   ei = (const int*)d_in[1];
    const int*   batch = (const int*)d_in[2];
    const float* W1 = (const float*)d_in[3];
    const float* b1 = (const float*)d_in[4];
    const float* W2 = (const float*)d_in[5];
    const float* b2 = (const float*)d_in[6];
    float* out = (float*)d_out;

    const int N = in_sizes[2];       // 50000 (assumed <= 65536)
    const int E = in_sizes[1] / 2;   // 800000
    const int G = out_size / 128;    // element count -> 128 graphs

    const int NB = (N + 255) >> 8;              // 196 buckets
    const int NBLK = (E + BCHUNK - 1) / BCHUNK; // 196 chunks
    const int ncounts = NB * NBLK;
    const int SRP = E + 7 * N + 16;             // padded srcs capacity

    // workspace layout (hb/ob have N+8 rows; row N is the sentinel zero row)
    _Float16* hb = (_Float16*)d_ws;                  // (N+8)*128 halves
    _Float16* ob = hb + (size_t)(N + 8) * 128;       // (N+8)*128 halves
    int* cnt  = (int*)(ob + (size_t)(N + 8) * 128);  // N
    int* row_start = cnt + N;                        // N
    float* dinv    = (float*)(row_start + N);        // N
    int* srcs      = (int*)(dinv + N);               // SRP
    unsigned int* bedges = (unsigned int*)(srcs + SRP); // E
    int* counts    = (int*)(bedges + E);             // NB*NBLK
    _Float16* wfrag1 = (_Float16*)(counts + ncounts);// 128*128
    float* P       = (float*)(wfrag1 + 128 * 128);   // 128*128 f32
    int* bsum      = (int*)(P + 128 * 128);          // <=64

    const int nbc = (ncounts + 1023) / 1024;  // <=64
    const int nbn = (N + 1023) / 1024;        // <=64

    bin_hist<<<NBLK, 256, 0, stream>>>(ei, W1, wfrag1, P, hb, ob, counts, E, N, NB, NBLK);
    block_sums<<<nbc, 256, 0, stream>>>(counts, bsum, ncounts);
    scan_bsum<<<1, 64, 0, stream>>>(bsum, nbc);
    scan_apply<<<nbc, 256, 0, stream>>>(counts, bsum, ncounts);
    bin_scatter<<<NBLK, 256, 0, stream>>>(ei, counts, bedges, E, NB, NBLK);
    deg_buckets<<<NB, 256, 0, stream>>>(bedges, counts, cnt, E, N, NB, NBLK);
    block_sums_pad<<<nbn, 256, 0, stream>>>(cnt, bsum, N);
    scan_bsum<<<1, 64, 0, stream>>>(bsum, nbn);
    scan_nodes<<<nbn, 256, 0, stream>>>(cnt, bsum, row_start, dinv, N);
    fill_buckets<<<NB, 256, 0, stream>>>(bedges, counts, row_start, cnt, srcs, E, N, NB, NBLK);

    gemm_mfma_f32in<<<(N + 127) / 128, 256, 0, stream>>>(x, wfrag1, dinv, hb, N);
    agg1<<<(N + 3) / 4, 256, 0, stream>>>(hb, srcs, row_start, cnt, dinv, b1, ob, N);
    agg2_pool<<<(N + 3) / 4, 256, 0, stream>>>(ob, srcs, row_start, cnt, dinv, batch, P, N);
    gemm_small<<<G, 128, 0, stream>>>(P, W2, b2, batch, out, N);
}

// Round 8
// 217.568 us; speedup vs baseline: 6.5580x; 1.0262x over previous
//
#include <hip/hip_runtime.h>
#include <hip/hip_bf16.h>

// GCN 2-layer + global_add_pool on MI355X.
// R14: segmented CSR — per-bucket fixed windows (BCAP edges in bedges,
// SCAP slots in srcs) make every preprocessing step bucket-local:
//  - scan_counts_seg: per-bucket scan of chunk counts (196 independent
//    blocks) replaces the 3-kernel global counts scan.
//  - build_csr: LDS degree hist -> LDS pad8 prefix -> scatter fill +
//    sentinel pad, one block per bucket; replaces deg_buckets +
//    block_sums_pad + scan_bsum + scan_nodes + fill_buckets.
// 14 dispatches -> 8. Agg/gemm kernels verbatim (gather16, MFMA).
// BCAP=8192 vs mean bucket load 4081 (64 sigma headroom on this input).

typedef _Float16 f16x8 __attribute__((ext_vector_type(8)));
typedef float f32x4 __attribute__((ext_vector_type(4)));

#define BCHUNK 4096

// ---------------- bin_hist + phase-0 init ----------------
__global__ __launch_bounds__(256) void bin_hist(const int* __restrict__ ei,
                                                const float* __restrict__ W1,
                                                _Float16* __restrict__ wfrag,
                                                float* __restrict__ P,
                                                _Float16* __restrict__ hb,
                                                _Float16* __restrict__ ob,
                                                int* __restrict__ counts,
                                                int E, int N, int NB, int NBLK) {
    __shared__ int hist[256];
    int t = threadIdx.x, blk = blockIdx.x;
    int gtid = blk * 256 + t;
    int gstride = gridDim.x * 256;

    // phase 0: independent init (P, sentinel rows, wfrag) — no grid deps
    for (int i = gtid; i < 128 * 128; i += gstride) P[i] = 0.f;
    if (gtid < 64) {
        ((unsigned int*)(hb + (size_t)N * 128))[gtid] = 0u;
        ((unsigned int*)(ob + (size_t)N * 128))[gtid] = 0u;
    }
    if (gtid < 2048) {
        int lane = gtid & 63, kc = (gtid >> 6) & 3, nb = gtid >> 8;
        int col = nb * 16 + (lane & 15);
        int krow = kc * 32 + (lane >> 4) * 8;
#pragma unroll
        for (int j = 0; j < 8; j++)
            wfrag[gtid * 8 + j] = (_Float16)W1[(krow + j) * 128 + col];
    }

    // bucket histogram
    for (int b = t; b < NB; b += 256) hist[b] = 0;
    __syncthreads();
    int base = blk * BCHUNK;
    int end = min(E, base + BCHUNK);
    for (int e = base + t; e < end; e += 256)
        atomicAdd(&hist[ei[E + e] >> 8], 1);
    __syncthreads();
    for (int b = t; b < NB; b += 256) counts[b * NBLK + blk] = hist[b];
}

// ---------------- per-bucket segmented scan of chunk counts ----------------
// Block b: exclusive-scan counts[b*NBLK .. b*NBLK+NBLK), add base b*BCAP,
// write total to btot[b]. No cross-block communication.
__global__ __launch_bounds__(256) void scan_counts_seg(int* __restrict__ counts,
                                                       int* __restrict__ btot,
                                                       int NBLK, int BCAP) {
    __shared__ int s[256];
    int b = blockIdx.x, t = threadIdx.x;
    int carry = 0;
    for (int base = 0; base < NBLK; base += 256) {
        int idx = base + t;
        int v = (idx < NBLK) ? counts[b * NBLK + idx] : 0;
        s[t] = v;
        __syncthreads();
        for (int off = 1; off < 256; off *= 2) {
            int u = (t >= off) ? s[t - off] : 0;
            __syncthreads();
            s[t] += u;
            __syncthreads();
        }
        int excl = s[t] - v + carry;
        if (idx < NBLK) counts[b * NBLK + idx] = b * BCAP + excl;
        carry += s[255];
        __syncthreads();
    }
    if (t == 0) btot[b] = carry;
}

// ---------------- bin_scatter (verbatim; cursors now segmented) ----------------
__global__ __launch_bounds__(256) void bin_scatter(const int* __restrict__ ei,
                                                   const int* __restrict__ counts,
                                                   unsigned int* __restrict__ bedges,
                                                   int E, int NB, int NBLK) {
    __shared__ int lcur[256];
    int t = threadIdx.x, blk = blockIdx.x;
    for (int b = t; b < NB; b += 256) lcur[b] = counts[b * NBLK + blk];
    __syncthreads();
    int base = blk * BCHUNK;
    int end = min(E, base + BCHUNK);
    for (int e = base + t; e < end; e += 256) {
        int s = ei[e];
        int d = ei[E + e];
        int pos = atomicAdd(&lcur[d >> 8], 1);
        bedges[pos] = (unsigned int)s | ((unsigned int)(d & 255) << 16);
    }
}

// ---------------- build_csr: degree hist + pad8 prefix + fill + pad ----------------
// One block per bucket; fully bucket-local (bedges window stays L2-hot
// between the two passes).
__global__ __launch_bounds__(256) void build_csr(const unsigned int* __restrict__ bedges,
                                                 const int* __restrict__ btot,
                                                 int* __restrict__ cnt,
                                                 int* __restrict__ row_start,
                                                 float* __restrict__ dinv,
                                                 int* __restrict__ srcs,
                                                 int N, int BCAP, int SCAP) {
    __shared__ int lcnt[256];
    __shared__ int lpre[256];
    __shared__ int lcur[256];
    int b = blockIdx.x, t = threadIdx.x;
    int node = (b << 8) + t;
    lcnt[t] = 0;
    __syncthreads();
    int bstart = b * BCAP;
    int bend = bstart + btot[b];
    for (int i = bstart + t; i < bend; i += 256)
        atomicAdd(&lcnt[bedges[i] >> 16], 1);
    __syncthreads();
    int c = lcnt[t];
    int pc = (c + 7) & ~7;
    lpre[t] = pc;
    __syncthreads();
    for (int off = 1; off < 256; off *= 2) {
        int u = (t >= off) ? lpre[t - off] : 0;
        __syncthreads();
        lpre[t] += u;
        __syncthreads();
    }
    int rs = b * SCAP + lpre[t] - pc;   // exclusive pad8 prefix + bucket base
    if (node < N) {
        row_start[node] = rs;
        cnt[node] = c;
        dinv[node] = rsqrtf((float)c + 1.0f);
    }
    lcur[t] = rs;
    __syncthreads();
    for (int i = bstart + t; i < bend; i += 256) {
        unsigned int p = bedges[i];
        int pos = atomicAdd(&lcur[p >> 16], 1);
        srcs[pos] = (int)(p & 0xffffu);
    }
    // pad region [rs+c, rs+pc) is disjoint from all scatter targets
    if (node < N) {
        for (int j = rs + c; j < rs + pc; j++) srcs[j] = N;  // sentinel zero row
    }
}

// ---------------- GEMM: C = dinv[row] * (A @ W), fp16 MFMA (verbatim) ----------------
__global__ __launch_bounds__(256) void gemm_mfma_f32in(const float* __restrict__ A,
                                                       const _Float16* __restrict__ wfrag,
                                                       const float* __restrict__ dinv,
                                                       _Float16* __restrict__ C, int M) {
    __shared__ _Float16 As[128 * 136];
    int t = threadIdx.x;
    int row0 = blockIdx.x * 128;

    const float4* A4 = (const float4*)A;
#pragma unroll
    for (int it = 0; it < 16; it++) {
        int v = it * 256 + t;
        int row = v >> 5;
        int seg = v & 31;
        float4 val = make_float4(0.f, 0.f, 0.f, 0.f);
        if (row0 + row < M) val = A4[(size_t)(row0 + row) * 32 + seg];
        _Float16* pp = &As[row * 136 + seg * 4];
        pp[0] = (_Float16)val.x; pp[1] = (_Float16)val.y;
        pp[2] = (_Float16)val.z; pp[3] = (_Float16)val.w;
    }
    __syncthreads();

    int wv = t >> 6;
    int lane = t & 63;
    int lrow = lane & 15;
    int lq = lane >> 4;

    f32x4 acc[2][8];
#pragma unroll
    for (int i = 0; i < 2; i++)
#pragma unroll
        for (int j = 0; j < 8; j++) acc[i][j] = (f32x4){0.f, 0.f, 0.f, 0.f};

#pragma unroll
    for (int kc = 0; kc < 4; kc++) {
        int k0 = kc * 32;
        f16x8 a0 = *((const f16x8*)&As[(wv * 32 + lrow) * 136 + k0 + lq * 8]);
        f16x8 a1 = *((const f16x8*)&As[(wv * 32 + 16 + lrow) * 136 + k0 + lq * 8]);
#pragma unroll
        for (int nb = 0; nb < 8; nb++) {
            f16x8 b = ((const f16x8*)wfrag)[(nb * 4 + kc) * 64 + lane];
            acc[0][nb] = __builtin_amdgcn_mfma_f32_16x16x32_f16(a0, b, acc[0][nb], 0, 0, 0);
            acc[1][nb] = __builtin_amdgcn_mfma_f32_16x16x32_f16(a1, b, acc[1][nb], 0, 0, 0);
        }
    }

#pragma unroll
    for (int ti = 0; ti < 2; ti++) {
#pragma unroll
        for (int r = 0; r < 4; r++) {
            int row = row0 + wv * 32 + ti * 16 + lq * 4 + r;
            if (row < M) {
                float dv = dinv[row];
#pragma unroll
                for (int nb = 0; nb < 8; nb++)
                    C[(size_t)row * 128 + nb * 16 + lrow] = (_Float16)(acc[ti][nb][r] * dv);
            }
        }
    }
}

// ---------------- agg1 (gather16, verbatim) ----------------
__global__ __launch_bounds__(256) void agg1(const _Float16* __restrict__ hb,
                                            const int* __restrict__ srcs,
                                            const int* __restrict__ row_start,
                                            const int* __restrict__ cnt,
                                            const float* __restrict__ dinv,
                                            const float* __restrict__ bias,
                                            _Float16* __restrict__ ob, int n) {
    int node = blockIdx.x * 4 + (threadIdx.x >> 6);
    if (node >= n) return;
    int lane = threadIdx.x & 63;
    int cc = lane & 15;
    int sg = lane >> 4;
    int s0 = row_start[node];
    int c = cnt[node];
    int nit = (c + 7) >> 3;
    float dn = dinv[node];

    float acc[8];
#pragma unroll
    for (int j = 0; j < 8; j++) acc[j] = 0.f;

    const int* sp = srcs + s0;
    int i0 = 0, i1 = 0;
    if (nit > 0) { i0 = sp[sg]; i1 = sp[4 + sg]; }
    for (int it = 0; it < nit; it++) {
        int cs0 = i0, cs1 = i1;
        int nxt = (it + 1 < nit) ? (it + 1) : it;
        i0 = sp[nxt * 8 + sg]; i1 = sp[nxt * 8 + 4 + sg];
        f16x8 v0 = *((const f16x8*)&hb[(size_t)(unsigned)cs0 * 128 + cc * 8]);
        f16x8 v1 = *((const f16x8*)&hb[(size_t)(unsigned)cs1 * 128 + cc * 8]);
#pragma unroll
        for (int j = 0; j < 8; j++) acc[j] += (float)v0[j];
#pragma unroll
        for (int j = 0; j < 8; j++) acc[j] += (float)v1[j];
    }
#pragma unroll
    for (int j = 0; j < 8; j++) {
        acc[j] += __shfl_xor(acc[j], 16);
        acc[j] += __shfl_xor(acc[j], 32);
    }
    f16x8 hs = *((const f16x8*)&hb[(size_t)node * 128 + cc * 8]);
    float4 b0 = ((const float4*)bias)[cc * 2];
    float4 b1v = ((const float4*)bias)[cc * 2 + 1];
    float bb[8] = {b0.x, b0.y, b0.z, b0.w, b1v.x, b1v.y, b1v.z, b1v.w};
    f16x8 o;
#pragma unroll
    for (int j = 0; j < 8; j++) {
        float tv = acc[j] + (float)hs[j];
        tv = fmaxf(fmaf(dn, tv, bb[j]), 0.f) * dn;
        o[j] = (_Float16)tv;
    }
    if (sg == 0) *((f16x8*)&ob[(size_t)node * 128 + cc * 8]) = o;
}

// ---------------- agg2 + pool (gather16, verbatim) ----------------
__global__ __launch_bounds__(256) void agg2_pool(const _Float16* __restrict__ ob,
                                                 const int* __restrict__ srcs,
                                                 const int* __restrict__ row_start,
                                                 const int* __restrict__ cnt,
                                                 const float* __restrict__ dinv,
                                                 const int* __restrict__ batch,
                                                 float* __restrict__ P, int n) {
    __shared__ float red[4][128];
    int wv = threadIdx.x >> 6;
    int lane = threadIdx.x & 63;
    int cc = lane & 15;
    int sg = lane >> 4;
    int base = blockIdx.x * 4;
    int node = base + wv;

    float t8[8];
#pragma unroll
    for (int j = 0; j < 8; j++) t8[j] = 0.f;
    int g = -1;

    if (node < n) {
        g = batch[node];
        int s0 = row_start[node];
        int c = cnt[node];
        int nit = (c + 7) >> 3;
        float dn = dinv[node];

        float acc[8];
#pragma unroll
        for (int j = 0; j < 8; j++) acc[j] = 0.f;
        const int* sp = srcs + s0;
        int i0 = 0, i1 = 0;
        if (nit > 0) { i0 = sp[sg]; i1 = sp[4 + sg]; }
        for (int it = 0; it < nit; it++) {
            int cs0 = i0, cs1 = i1;
            int nxt = (it + 1 < nit) ? (it + 1) : it;
            i0 = sp[nxt * 8 + sg]; i1 = sp[nxt * 8 + 4 + sg];
            f16x8 v0 = *((const f16x8*)&ob[(size_t)(unsigned)cs0 * 128 + cc * 8]);
            f16x8 v1 = *((const f16x8*)&ob[(size_t)(unsigned)cs1 * 128 + cc * 8]);
#pragma unroll
            for (int j = 0; j < 8; j++) acc[j] += (float)v0[j];
#pragma unroll
            for (int j = 0; j < 8; j++) acc[j] += (float)v1[j];
        }
#pragma unroll
        for (int j = 0; j < 8; j++) {
            acc[j] += __shfl_xor(acc[j], 16);
            acc[j] += __shfl_xor(acc[j], 32);
        }
        f16x8 hs = *((const f16x8*)&ob[(size_t)node * 128 + cc * 8]);
#pragma unroll
        for (int j = 0; j < 8; j++) t8[j] = dn * (acc[j] + (float)hs[j]);
    }

    int lastn = min(base + 3, n - 1);
    bool uniform = (base < n) && (batch[base] == batch[lastn]) && (base + 3 < n);
    if (uniform) {
        if (sg == 0) {
#pragma unroll
            for (int j = 0; j < 8; j++) red[wv][cc * 8 + j] = t8[j];
        }
        __syncthreads();
        if (wv == 0) {
            int col = lane * 2;
            float sx = red[0][col] + red[1][col] + red[2][col] + red[3][col];
            float sy = red[0][col + 1] + red[1][col + 1] + red[2][col + 1] + red[3][col + 1];
            atomicAdd(&P[g * 128 + col], sx);
            atomicAdd(&P[g * 128 + col + 1], sy);
        }
    } else if (node < n) {
        if (sg == 0) {
#pragma unroll
            for (int j = 0; j < 8; j++) atomicAdd(&P[g * 128 + cc * 8 + j], t8[j]);
        }
    }
}

// ---------------- out = P @ W2 + n_g * b2 (verbatim) ----------------
__global__ __launch_bounds__(128) void gemm_small(const float* __restrict__ P,
                                                  const float* __restrict__ W2,
                                                  const float* __restrict__ b2,
                                                  const int* __restrict__ batch,
                                                  float* __restrict__ out, int n) {
    __shared__ float prow[128];
    int g = blockIdx.x;
    int c = threadIdx.x;
    prow[c] = P[g * 128 + c];
    __syncthreads();
    int lo = 0, hi = n;
    while (lo < hi) { int mid = (lo + hi) >> 1; if (batch[mid] < g) lo = mid + 1; else hi = mid; }
    int start = lo;
    hi = n;
    while (lo < hi) { int mid = (lo + hi) >> 1; if (batch[mid] < g + 1) lo = mid + 1; else hi = mid; }
    float ng = (float)(lo - start);
    float acc = 0.f;
#pragma unroll 8
    for (int k = 0; k < 128; k++) acc = fmaf(prow[k], W2[k * 128 + c], acc);
    out[g * 128 + c] = acc + ng * b2[c];
}

extern "C" void kernel_launch(void* const* d_in, const int* in_sizes, int n_in,
                              void* d_out, int out_size, void* d_ws, size_t ws_size,
                              hipStream_t stream) {
    const float* x  = (const float*)d_in[0];
    const int*   ei = (const int*)d_in[1];
    const int*   batch = (const int*)d_in[2];
    const float* W1 = (const float*)d_in[3];
    const float* b1 = (const float*)d_in[4];
    const float* W2 = (const float*)d_in[5];
    const float* b2 = (const float*)d_in[6];
    float* out = (float*)d_out;

    const int N = in_sizes[2];       // 50000 (assumed <= 65536)
    const int E = in_sizes[1] / 2;   // 800000
    const int G = out_size / 128;    // element count -> 128 graphs

    const int NB = (N + 255) >> 8;              // 196 buckets
    const int NBLK = (E + BCHUNK - 1) / BCHUNK; // 196 chunks
    const int ncounts = NB * NBLK;
    const int BCAP = 8192;                      // per-bucket edge window
    const int SCAP = BCAP + 2048;               // per-bucket srcs window (pad8)

    // workspace layout (hb/ob have N+8 rows; row N is the sentinel zero row)
    _Float16* hb = (_Float16*)d_ws;                  // (N+8)*128 halves
    _Float16* ob = hb + (size_t)(N + 8) * 128;       // (N+8)*128 halves
    int* cnt  = (int*)(ob + (size_t)(N + 8) * 128);  // N
    int* row_start = cnt + N;                        // N
    float* dinv    = (float*)(row_start + N);        // N
    int* srcs      = (int*)(dinv + N);               // NB*SCAP
    unsigned int* bedges = (unsigned int*)(srcs + (size_t)NB * SCAP); // NB*BCAP
    int* counts    = (int*)(bedges + (size_t)NB * BCAP); // NB*NBLK
    int* btot      = counts + ncounts;               // NB
    _Float16* wfrag1 = (_Float16*)(btot + NB);       // 128*128
    float* P       = (float*)(wfrag1 + 128 * 128);   // 128*128 f32

    bin_hist<<<NBLK, 256, 0, stream>>>(ei, W1, wfrag1, P, hb, ob, counts, E, N, NB, NBLK);
    scan_counts_seg<<<NB, 256, 0, stream>>>(counts, btot, NBLK, BCAP);
    bin_scatter<<<NBLK, 256, 0, stream>>>(ei, counts, bedges, E, NB, NBLK);
    build_csr<<<NB, 256, 0, stream>>>(bedges, btot, cnt, row_start, dinv, srcs, N, BCAP, SCAP);

    gemm_mfma_f32in<<<(N + 127) / 128, 256, 0, stream>>>(x, wfrag1, dinv, hb, N);
    agg1<<<(N + 3) / 4, 256, 0, stream>>>(hb, srcs, row_start, cnt, dinv, b1, ob, N);
    agg2_pool<<<(N + 3) / 4, 256, 0, stream>>>(ob, srcs, row_start, cnt, dinv, batch, P, N);
    gemm_small<<<G, 128, 0, stream>>>(P, W2, b2, batch, out, N);
}